// Round 1
// baseline (1927.112 us; speedup 1.0000x reference)
//
#include <hip/hip_runtime.h>
#include <math.h>

#define D_CHEB 30

struct Cheb {
    float c[D_CHEB + 1];
    float sm;   // scale for A in S2 = sm*A + sbd*I  (S2 = 2t)
    float sbd;  // diagonal offset (includes EPS fold-in)
};

// ---------------------------------------------------------------------------
// Kernel 1: bimap. grid (m=64, b=32, s=2). Computes K, V (and Q for s=1,m=63)
// mats layout: [0..4095] K (b*128 + s*64 + m), [4096..8191] V, [8192..8223] Q
// ---------------------------------------------------------------------------
__global__ __launch_bounds__(256) void bimap_kernel(
    const float* __restrict__ x1, const float* __restrict__ x2,
    const float* __restrict__ wk1, const float* __restrict__ wv1,
    const float* __restrict__ wk2, const float* __restrict__ wv2,
    const float* __restrict__ wq2,
    float* __restrict__ mats)
{
    __shared__ float xs[96][97];
    __shared__ float wsh[48][97];
    __shared__ float Ts[48][97];
    const int m = blockIdx.x, b = blockIdx.y, s = blockIdx.z;
    const int tid = threadIdx.x;
    const float* x = (s ? x2 : x1) + (size_t)(b * 64 + m) * 9216;
    for (int e = tid; e < 9216; e += 256) xs[e / 96][e % 96] = x[e];
    const int npass = (s == 1 && m == 63) ? 3 : 2;
    const int tr = tid >> 4, tc = tid & 15;
    const int o0 = tr * 3;
    for (int pass = 0; pass < npass; ++pass) {
        const float* w = (pass == 0) ? (s ? wk2 : wk1)
                       : (pass == 1) ? (s ? wv2 : wv1) : wq2;
        __syncthreads();  // prev pass done reading wsh/Ts (and xs loaded, pass 0)
        for (int e = tid; e < 4608; e += 256) wsh[e / 96][e % 96] = w[e];
        __syncthreads();
        // T = w @ x  (48x96), tiles 3 rows x 6 cols
        {
            const int j0 = tc * 6;
            float acc[3][6];
            #pragma unroll
            for (int i = 0; i < 3; ++i)
                #pragma unroll
                for (int j = 0; j < 6; ++j) acc[i][j] = 0.f;
            for (int i = 0; i < 96; ++i) {
                float a0 = wsh[o0][i], a1 = wsh[o0 + 1][i], a2 = wsh[o0 + 2][i];
                #pragma unroll
                for (int j = 0; j < 6; ++j) {
                    float bv = xs[i][j0 + j];
                    acc[0][j] += a0 * bv; acc[1][j] += a1 * bv; acc[2][j] += a2 * bv;
                }
            }
            #pragma unroll
            for (int i = 0; i < 3; ++i)
                #pragma unroll
                for (int j = 0; j < 6; ++j) Ts[o0 + i][j0 + j] = acc[i][j];
        }
        __syncthreads();
        // K = T @ w^T (48x48), tiles 3x3
        {
            const int p0 = tc * 3;
            float acc[3][3];
            #pragma unroll
            for (int i = 0; i < 3; ++i)
                #pragma unroll
                for (int j = 0; j < 3; ++j) acc[i][j] = 0.f;
            for (int j = 0; j < 96; ++j) {
                float t0 = Ts[o0][j], t1 = Ts[o0 + 1][j], t2 = Ts[o0 + 2][j];
                float w0 = wsh[p0][j], w1 = wsh[p0 + 1][j], w2 = wsh[p0 + 2][j];
                acc[0][0] += t0 * w0; acc[0][1] += t0 * w1; acc[0][2] += t0 * w2;
                acc[1][0] += t1 * w0; acc[1][1] += t1 * w1; acc[1][2] += t1 * w2;
                acc[2][0] += t2 * w0; acc[2][1] += t2 * w1; acc[2][2] += t2 * w2;
            }
            size_t idx = (pass == 0) ? (size_t)(b * 128 + s * 64 + m)
                       : (pass == 1) ? (size_t)(4096 + b * 128 + s * 64 + m)
                                     : (size_t)(8192 + b);
            float* out = mats + idx * 2304;
            #pragma unroll
            for (int i = 0; i < 3; ++i)
                #pragma unroll
                for (int j = 0; j < 3; ++j) out[(o0 + i) * 48 + p0 + j] = acc[i][j];
        }
    }
}

// ---------------------------------------------------------------------------
// Kernel 2: matrix log via Chebyshev-Clenshaw, in place. One block per matrix.
// ---------------------------------------------------------------------------
__global__ __launch_bounds__(256) void logm_kernel(float* __restrict__ mats, Cheb co)
{
    __shared__ float S2[48][49];
    __shared__ float Ba[48][49];
    __shared__ float Bb[48][49];
    const int tid = threadIdx.x;
    float* A = mats + (size_t)blockIdx.x * 2304;
    for (int e = tid; e < 2304; e += 256) {
        int r = e / 48, c = e % 48;
        float v = A[e];
        S2[r][c] = co.sm * v + ((r == c) ? co.sbd : 0.f);
        Ba[r][c] = (r == c) ? co.c[D_CHEB] : 0.f;  // y_D = c_D * I
        Bb[r][c] = 0.f;                            // y_{D+1} = 0
    }
    __syncthreads();
    const int tr = tid >> 4, tc = tid & 15;
    const int r0 = tr * 3, c0 = tc * 3;
    float* cur = &Ba[0][0];  // y_{k+1}
    float* prv = &Bb[0][0];  // y_{k+2}
    for (int k = D_CHEB - 1; k >= 1; --k) {
        const float ck = co.c[k];
        float acc[3][3];
        #pragma unroll
        for (int i = 0; i < 3; ++i)
            #pragma unroll
            for (int j = 0; j < 3; ++j)
                acc[i][j] = ((r0 + i) == (c0 + j) ? ck : 0.f) - prv[(r0 + i) * 49 + (c0 + j)];
        #pragma unroll 4
        for (int kk = 0; kk < 48; ++kk) {
            float a0 = S2[r0][kk], a1 = S2[r0 + 1][kk], a2 = S2[r0 + 2][kk];
            float b0 = cur[kk * 49 + c0], b1 = cur[kk * 49 + c0 + 1], b2 = cur[kk * 49 + c0 + 2];
            acc[0][0] += a0 * b0; acc[0][1] += a0 * b1; acc[0][2] += a0 * b2;
            acc[1][0] += a1 * b0; acc[1][1] += a1 * b1; acc[1][2] += a1 * b2;
            acc[2][0] += a2 * b0; acc[2][1] += a2 * b1; acc[2][2] += a2 * b2;
        }
        #pragma unroll
        for (int i = 0; i < 3; ++i)
            #pragma unroll
            for (int j = 0; j < 3; ++j) prv[(r0 + i) * 49 + (c0 + j)] = acc[i][j];
        __syncthreads();
        float* t = cur; cur = prv; prv = t;
    }
    // p = c0*I + 0.5*S2*y1 - y2
    {
        float macc[3][3];
        #pragma unroll
        for (int i = 0; i < 3; ++i)
            #pragma unroll
            for (int j = 0; j < 3; ++j) macc[i][j] = 0.f;
        #pragma unroll 4
        for (int kk = 0; kk < 48; ++kk) {
            float a0 = S2[r0][kk], a1 = S2[r0 + 1][kk], a2 = S2[r0 + 2][kk];
            float b0 = cur[kk * 49 + c0], b1 = cur[kk * 49 + c0 + 1], b2 = cur[kk * 49 + c0 + 2];
            macc[0][0] += a0 * b0; macc[0][1] += a0 * b1; macc[0][2] += a0 * b2;
            macc[1][0] += a1 * b0; macc[1][1] += a1 * b1; macc[1][2] += a1 * b2;
            macc[2][0] += a2 * b0; macc[2][1] += a2 * b1; macc[2][2] += a2 * b2;
        }
        #pragma unroll
        for (int i = 0; i < 3; ++i)
            #pragma unroll
            for (int j = 0; j < 3; ++j) {
                float v = ((r0 + i) == (c0 + j) ? co.c[0] : 0.f)
                        - prv[(r0 + i) * 49 + (c0 + j)] + 0.5f * macc[i][j];
                A[(r0 + i) * 48 + (c0 + j)] = v;
            }
    }
}

// ---------------------------------------------------------------------------
// Kernel 3: energies + softmax + mixed. One block per batch b.
// ---------------------------------------------------------------------------
__global__ __launch_bounds__(256) void attn_kernel(const float* __restrict__ mats,
                                                   float* __restrict__ mixed)
{
    __shared__ float q[2304];
    __shared__ float sc[128];
    __shared__ float red[4];
    const int b = blockIdx.x, tid = threadIdx.x;
    const int wid = tid >> 6, lane = tid & 63;
    const float* logQ = mats + (size_t)(8192 + b) * 2304;
    for (int e = tid; e < 2304; e += 256) q[e] = logQ[e];
    __syncthreads();
    for (int i = wid; i < 128; i += 4) {
        const float* K = mats + (size_t)(b * 128 + i) * 2304;
        float p = 0.f;
        for (int e = lane; e < 2304; e += 64) { float d = K[e] - q[e]; p += d * d; }
        #pragma unroll
        for (int off = 32; off >= 1; off >>= 1) p += __shfl_down(p, off, 64);
        if (lane == 0) {
            float en = fmaxf(p, 0.f);
            sc[i] = 1.f / (1.f + log1pf(en));
        }
    }
    __syncthreads();
    // softmax over i = 0..127
    float v = (tid < 128) ? sc[tid] : -3.4e38f;
    #pragma unroll
    for (int off = 32; off >= 1; off >>= 1) v = fmaxf(v, __shfl_xor(v, off, 64));
    if (lane == 0) red[wid] = v;
    __syncthreads();
    float gmax = fmaxf(fmaxf(red[0], red[1]), fmaxf(red[2], red[3]));
    __syncthreads();
    float ex = (tid < 128) ? expf(sc[tid] - gmax) : 0.f;
    float sum = ex;
    #pragma unroll
    for (int off = 32; off >= 1; off >>= 1) sum += __shfl_xor(sum, off, 64);
    if (lane == 0) red[wid] = sum;
    __syncthreads();
    float gsum = red[0] + red[1] + red[2] + red[3];
    if (tid < 128) sc[tid] = ex / gsum;
    __syncthreads();
    // mixed = sum_i w_i * logV_i ; each thread owns elems tid + 256*j
    float acc[9];
    #pragma unroll
    for (int j = 0; j < 9; ++j) acc[j] = 0.f;
    for (int i = 0; i < 128; ++i) {
        float w = sc[i];
        const float* V = mats + (size_t)(4096 + b * 128 + i) * 2304;
        #pragma unroll
        for (int j = 0; j < 9; ++j) acc[j] += w * V[tid + 256 * j];
    }
    float* o = mixed + (size_t)b * 2304;
    #pragma unroll
    for (int j = 0; j < 9; ++j) o[tid + 256 * j] = acc[j];
}

// ---------------------------------------------------------------------------
// Kernel 4: expm via scaling-squaring Taylor (s=2, degree 12). One block per b.
// ---------------------------------------------------------------------------
__global__ __launch_bounds__(256) void expm_kernel(const float* __restrict__ mixed,
                                                   float* __restrict__ out)
{
    __shared__ float Bs[48][49];
    __shared__ float Ra[48][49];
    __shared__ float Rb[48][49];
    const int b = blockIdx.x, tid = threadIdx.x;
    const float* M = mixed + (size_t)b * 2304;
    for (int e = tid; e < 2304; e += 256) {
        int r = e / 48, c = e % 48;
        float v = 0.25f * M[e];
        Bs[r][c] = v;
        Ra[r][c] = ((r == c) ? 1.f : 0.f) + v * (1.f / 12.f);  // I + B/12
    }
    __syncthreads();
    const int tr = tid >> 4, tc = tid & 15;
    const int r0 = tr * 3, c0 = tc * 3;
    float* cur = &Ra[0][0];
    float* nxt = &Rb[0][0];
    for (int k = 11; k >= 1; --k) {
        const float invk = 1.f / (float)k;
        float acc[3][3];
        #pragma unroll
        for (int i = 0; i < 3; ++i)
            #pragma unroll
            for (int j = 0; j < 3; ++j) acc[i][j] = 0.f;
        #pragma unroll 4
        for (int kk = 0; kk < 48; ++kk) {
            float a0 = Bs[r0][kk], a1 = Bs[r0 + 1][kk], a2 = Bs[r0 + 2][kk];
            float b0 = cur[kk * 49 + c0], b1 = cur[kk * 49 + c0 + 1], b2 = cur[kk * 49 + c0 + 2];
            acc[0][0] += a0 * b0; acc[0][1] += a0 * b1; acc[0][2] += a0 * b2;
            acc[1][0] += a1 * b0; acc[1][1] += a1 * b1; acc[1][2] += a1 * b2;
            acc[2][0] += a2 * b0; acc[2][1] += a2 * b1; acc[2][2] += a2 * b2;
        }
        #pragma unroll
        for (int i = 0; i < 3; ++i)
            #pragma unroll
            for (int j = 0; j < 3; ++j)
                nxt[(r0 + i) * 49 + (c0 + j)] =
                    ((r0 + i) == (c0 + j) ? 1.f : 0.f) + acc[i][j] * invk;
        __syncthreads();
        float* t = cur; cur = nxt; nxt = t;
    }
    // square twice
    for (int sq = 0; sq < 2; ++sq) {
        float acc[3][3];
        #pragma unroll
        for (int i = 0; i < 3; ++i)
            #pragma unroll
            for (int j = 0; j < 3; ++j) acc[i][j] = 0.f;
        #pragma unroll 4
        for (int kk = 0; kk < 48; ++kk) {
            float a0 = cur[(r0) * 49 + kk], a1 = cur[(r0 + 1) * 49 + kk], a2 = cur[(r0 + 2) * 49 + kk];
            float b0 = cur[kk * 49 + c0], b1 = cur[kk * 49 + c0 + 1], b2 = cur[kk * 49 + c0 + 2];
            acc[0][0] += a0 * b0; acc[0][1] += a0 * b1; acc[0][2] += a0 * b2;
            acc[1][0] += a1 * b0; acc[1][1] += a1 * b1; acc[1][2] += a1 * b2;
            acc[2][0] += a2 * b0; acc[2][1] += a2 * b1; acc[2][2] += a2 * b2;
        }
        __syncthreads();  // everyone done reading cur
        #pragma unroll
        for (int i = 0; i < 3; ++i)
            #pragma unroll
            for (int j = 0; j < 3; ++j) nxt[(r0 + i) * 49 + (c0 + j)] = acc[i][j];
        __syncthreads();
        float* t = cur; cur = nxt; nxt = t;
    }
    #pragma unroll
    for (int i = 0; i < 3; ++i)
        #pragma unroll
        for (int j = 0; j < 3; ++j)
            out[(size_t)b * 2304 + (r0 + i) * 48 + (c0 + j)] = cur[(r0 + i) * 49 + (c0 + j)];
}

// ---------------------------------------------------------------------------
extern "C" void kernel_launch(void* const* d_in, const int* in_sizes, int n_in,
                              void* d_out, int out_size, void* d_ws, size_t ws_size,
                              hipStream_t stream)
{
    (void)in_sizes; (void)n_in; (void)out_size; (void)ws_size;
    const float* x1  = (const float*)d_in[0];
    const float* x2  = (const float*)d_in[1];
    // d_in[2] = wq1 : unused (only query j=127 survives -> wq2 path)
    const float* wk1 = (const float*)d_in[3];
    const float* wv1 = (const float*)d_in[4];
    const float* wq2 = (const float*)d_in[5];
    const float* wk2 = (const float*)d_in[6];
    const float* wv2 = (const float*)d_in[7];
    float* mats  = (float*)d_ws;                    // [8224][2304] K,V,Q
    float* mixed = mats + (size_t)8224 * 2304;      // [32][2304]
    float* out   = (float*)d_out;

    Cheb co;
    {
        const double a = 0.098, bb = 5.5;
        const int N = 256;
        for (int k = 0; k <= D_CHEB; ++k) {
            double sacc = 0.0;
            for (int j = 0; j < N; ++j) {
                double th = M_PI * (j + 0.5) / N;
                double xj = 0.5 * (a + bb) + 0.5 * (bb - a) * cos(th);
                sacc += log(xj) * cos(k * th);
            }
            double ck = 2.0 * sacc / N;
            if (k == 0) ck *= 0.5;
            co.c[k] = (float)ck;
        }
        co.sm  = (float)(4.0 / (bb - a));
        co.sbd = (float)((4.0 * 1e-6 - 2.0 * (a + bb)) / (bb - a));
    }

    bimap_kernel<<<dim3(64, 32, 2), 256, 0, stream>>>(x1, x2, wk1, wv1, wk2, wv2, wq2, mats);
    logm_kernel<<<8224, 256, 0, stream>>>(mats, co);
    attn_kernel<<<32, 256, 0, stream>>>(mats, mixed);
    expm_kernel<<<32, 256, 0, stream>>>(mixed, out);
}

// Round 2
// 959.455 us; speedup vs baseline: 2.0085x; 2.0085x over previous
//
#include <hip/hip_runtime.h>
#include <math.h>

#define D_CHEB 24
#define LPAD 52   // row pad (floats) for 48-col LDS arrays
#define TPAD 52   // row pad for Tt (96x48) in bimap

struct Cheb {
    float c[D_CHEB + 1];
    float sm;   // S2 = sm*A + sbd*I  (S2 = 2t, t scaled to [-1,1])
    float sbd;
};

// load 6 consecutive floats (8B-aligned) as 3 float2 into dst[0..5]
#define LD6(dst, base, off) {                                   \
    float2 _t0 = *(const float2*)((base) + (off));              \
    float2 _t1 = *(const float2*)((base) + (off) + 2);          \
    float2 _t2 = *(const float2*)((base) + (off) + 4);          \
    dst[0]=_t0.x; dst[1]=_t0.y; dst[2]=_t1.x;                   \
    dst[3]=_t1.y; dst[4]=_t2.x; dst[5]=_t2.y; }

// acc += (HALF? 0.5:1) * Ash * Bsh  (48x48, Ash symmetric-read by rows)
template<bool HALF>
__device__ __forceinline__ void mm48(const float* Ash, const float* Bsh,
                                     int r0, int c0, float acc[6][6])
{
    #pragma unroll 8
    for (int kk = 0; kk < 48; ++kk) {
        float a[6], b[6];
        LD6(a, Ash, kk * LPAD + r0);
        LD6(b, Bsh, kk * LPAD + c0);
        if (HALF) {
            #pragma unroll
            for (int i = 0; i < 6; ++i) a[i] *= 0.5f;
        }
        #pragma unroll
        for (int i = 0; i < 6; ++i)
            #pragma unroll
            for (int j = 0; j < 6; ++j)
                acc[i][j] = fmaf(a[i], b[j], acc[i][j]);
    }
}

// ---------------------------------------------------------------------------
// transpose W (48x96 row-major) -> Wt (96x48), 5 matrices
// ---------------------------------------------------------------------------
__global__ __launch_bounds__(256) void transpose_w(
    const float* __restrict__ w0, const float* __restrict__ w1,
    const float* __restrict__ w2, const float* __restrict__ w3,
    const float* __restrict__ w4, float* __restrict__ wt)
{
    const float* W = (blockIdx.x == 0) ? w0 : (blockIdx.x == 1) ? w1
                   : (blockIdx.x == 2) ? w2 : (blockIdx.x == 3) ? w3 : w4;
    float* D = wt + blockIdx.x * 4608;
    for (int e = threadIdx.x; e < 4608; e += 256)
        D[(e % 96) * 48 + e / 96] = W[e];
}

// ---------------------------------------------------------------------------
// bimap: one wave per matrix(-pair). bid<4096: K and V. bid>=4096: Q.
// mats: [0..4095] K (b*128+s*64+m), [4096..8191] V, [8192..8223] Q
// ---------------------------------------------------------------------------
__global__ __launch_bounds__(64, 2) void bimap_kernel(
    const float* __restrict__ x1, const float* __restrict__ x2,
    const float* __restrict__ wt, float* __restrict__ mats)
{
    __shared__ float Tt[96 * TPAD];  // T transposed: Tt[c][r], c<96, r<48
    const int bid = blockIdx.x, tid = threadIdx.x;
    const int ty = tid >> 3, tx = tid & 7;
    const int r0 = ty * 6;

    const float* x; const float* W[2]; size_t oo[2]; int npass;
    if (bid < 4096) {
        int b = bid >> 7, s = (bid >> 6) & 1, m = bid & 63;
        x = (s ? x2 : x1) + (size_t)(b * 64 + m) * 9216;
        W[0] = wt + (s ? 2 : 0) * 4608;  // wk
        W[1] = wt + (s ? 3 : 1) * 4608;  // wv
        oo[0] = (size_t)bid; oo[1] = (size_t)(4096 + bid); npass = 2;
    } else {
        int b = bid - 4096;
        x = x2 + (size_t)(b * 64 + 63) * 9216;
        W[0] = wt + 4 * 4608; W[1] = W[0];
        oo[0] = (size_t)(8192 + b); oo[1] = oo[0]; npass = 1;
    }

    for (int pass = 0; pass < npass; ++pass) {
        const float* Wt = W[pass];
        // phase 1: T = W @ x ; tile 6 rows x 12 cols per lane
        const int cx = tx * 12;
        {
            float acc[6][12];
            #pragma unroll
            for (int i = 0; i < 6; ++i)
                #pragma unroll
                for (int j = 0; j < 12; ++j) acc[i][j] = 0.f;
            #pragma unroll 4
            for (int kk = 0; kk < 96; ++kk) {
                float a[6];
                LD6(a, Wt, kk * 48 + r0);
                float4 b0 = *(const float4*)(x + kk * 96 + cx);
                float4 b1 = *(const float4*)(x + kk * 96 + cx + 4);
                float4 b2 = *(const float4*)(x + kk * 96 + cx + 8);
                float b[12] = {b0.x,b0.y,b0.z,b0.w, b1.x,b1.y,b1.z,b1.w,
                               b2.x,b2.y,b2.z,b2.w};
                #pragma unroll
                for (int i = 0; i < 6; ++i)
                    #pragma unroll
                    for (int j = 0; j < 12; ++j)
                        acc[i][j] = fmaf(a[i], b[j], acc[i][j]);
            }
            #pragma unroll
            for (int i = 0; i < 6; ++i)
                #pragma unroll
                for (int j = 0; j < 12; ++j)
                    Tt[(cx + j) * TPAD + r0 + i] = acc[i][j];
        }
        // phase 2: out = T @ W^T ; tile 6x6 per lane
        {
            const int p0 = tx * 6;
            float acc[6][6];
            #pragma unroll
            for (int i = 0; i < 6; ++i)
                #pragma unroll
                for (int j = 0; j < 6; ++j) acc[i][j] = 0.f;
            #pragma unroll 8
            for (int j = 0; j < 96; ++j) {
                float a[6], b[6];
                LD6(a, Tt, j * TPAD + r0);
                LD6(b, Wt, j * 48 + p0);
                #pragma unroll
                for (int i = 0; i < 6; ++i)
                    #pragma unroll
                    for (int jj = 0; jj < 6; ++jj)
                        acc[i][jj] = fmaf(a[i], b[jj], acc[i][jj]);
            }
            float* out = mats + oo[pass] * 2304;
            #pragma unroll
            for (int i = 0; i < 6; ++i)
                #pragma unroll
                for (int q = 0; q < 3; ++q)
                    *(float2*)(out + (r0 + i) * 48 + p0 + 2 * q) =
                        make_float2(acc[i][2 * q], acc[i][2 * q + 1]);
        }
    }
}

// ---------------------------------------------------------------------------
// logm: Chebyshev-Clenshaw, one wave per matrix, in place. No barriers.
// ---------------------------------------------------------------------------
__global__ __launch_bounds__(64, 2) void logm_kernel(float* __restrict__ mats, Cheb co)
{
    __shared__ float S2[48 * LPAD];
    __shared__ float Ysh[48 * LPAD];
    const int tid = threadIdx.x;
    const int ty = tid >> 3, tx = tid & 7;
    const int r0 = ty * 6, c0 = tx * 6;
    float* A = mats + (size_t)blockIdx.x * 2304;

    const float cD = co.c[D_CHEB], cD1 = co.c[D_CHEB - 1];
    // load A -> S2 = sm*A + sbd*I ; seed Y = y_{D-1} = c_{D-1}*I + c_D*S2
    #pragma unroll
    for (int j = 0; j < 9; ++j) {
        int f = (tid + 64 * j) * 4;
        int r = f / 48, c = f % 48;
        float4 v = *(const float4*)(A + f);
        float vv[4] = {v.x, v.y, v.z, v.w};
        float s[4], y[4];
        #pragma unroll
        for (int q = 0; q < 4; ++q) {
            bool d = (r == c + q);
            s[q] = co.sm * vv[q] + (d ? co.sbd : 0.f);
            y[q] = cD * s[q] + (d ? cD1 : 0.f);
        }
        *(float4*)&S2[r * LPAD + c]  = make_float4(s[0], s[1], s[2], s[3]);
        *(float4*)&Ysh[r * LPAD + c] = make_float4(y[0], y[1], y[2], y[3]);
    }
    // P = y_D tile = c_D * I
    float P[6][6];
    #pragma unroll
    for (int i = 0; i < 6; ++i)
        #pragma unroll
        for (int j = 0; j < 6; ++j)
            P[i][j] = (r0 + i == c0 + j) ? cD : 0.f;

    for (int k = D_CHEB - 2; k >= 1; --k) {
        const float ck = co.c[k];
        float acc[6][6];
        #pragma unroll
        for (int i = 0; i < 6; ++i)
            #pragma unroll
            for (int j = 0; j < 6; ++j)
                acc[i][j] = ((r0 + i == c0 + j) ? ck : 0.f) - P[i][j];
        mm48<false>(S2, Ysh, r0, c0, acc);
        // P <- old Y tile (own region), then overwrite with acc
        #pragma unroll
        for (int i = 0; i < 6; ++i) {
            LD6(P[i], Ysh, (r0 + i) * LPAD + c0);
            #pragma unroll
            for (int q = 0; q < 3; ++q)
                *(float2*)&Ysh[(r0 + i) * LPAD + c0 + 2 * q] =
                    make_float2(acc[i][2 * q], acc[i][2 * q + 1]);
        }
    }
    // final: p = c0*I - P + 0.5*S2*Y  -> global
    {
        float acc[6][6];
        #pragma unroll
        for (int i = 0; i < 6; ++i)
            #pragma unroll
            for (int j = 0; j < 6; ++j)
                acc[i][j] = ((r0 + i == c0 + j) ? co.c[0] : 0.f) - P[i][j];
        mm48<true>(S2, Ysh, r0, c0, acc);
        #pragma unroll
        for (int i = 0; i < 6; ++i)
            #pragma unroll
            for (int q = 0; q < 3; ++q)
                *(float2*)(A + (r0 + i) * 48 + c0 + 2 * q) =
                    make_float2(acc[i][2 * q], acc[i][2 * q + 1]);
    }
}

// ---------------------------------------------------------------------------
// attention, split: energy (4096 waves) -> softmax (32 waves) -> mix (288 blk)
// ---------------------------------------------------------------------------
__global__ __launch_bounds__(64) void energy_kernel(const float* __restrict__ mats,
                                                    float* __restrict__ sc)
{
    const int i = blockIdx.x, b = blockIdx.y, lane = threadIdx.x;
    const float* K = mats + (size_t)(b * 128 + i) * 2304;
    const float* Q = mats + (size_t)(8192 + b) * 2304;
    float p = 0.f;
    #pragma unroll
    for (int j = 0; j < 9; ++j) {
        int f = (lane + 64 * j) * 4;
        float4 kv = *(const float4*)(K + f);
        float4 qv = *(const float4*)(Q + f);
        float dx = kv.x - qv.x, dy = kv.y - qv.y, dz = kv.z - qv.z, dw = kv.w - qv.w;
        p += dx * dx + dy * dy + dz * dz + dw * dw;
    }
    #pragma unroll
    for (int off = 32; off >= 1; off >>= 1) p += __shfl_xor(p, off, 64);
    if (lane == 0)
        sc[b * 128 + i] = 1.f / (1.f + log1pf(fmaxf(p, 0.f)));
}

__global__ __launch_bounds__(64) void softmax_kernel(float* __restrict__ sc)
{
    const int b = blockIdx.x, lane = threadIdx.x;
    float s0 = sc[b * 128 + lane], s1 = sc[b * 128 + 64 + lane];
    float m = fmaxf(s0, s1);
    #pragma unroll
    for (int off = 32; off >= 1; off >>= 1) m = fmaxf(m, __shfl_xor(m, off, 64));
    float e0 = expf(s0 - m), e1 = expf(s1 - m);
    float sum = e0 + e1;
    #pragma unroll
    for (int off = 32; off >= 1; off >>= 1) sum += __shfl_xor(sum, off, 64);
    sc[b * 128 + lane] = e0 / sum;
    sc[b * 128 + 64 + lane] = e1 / sum;
}

__global__ __launch_bounds__(256) void mix_kernel(const float* __restrict__ mats,
                                                  const float* __restrict__ sc,
                                                  float* __restrict__ mixed)
{
    __shared__ float w[128];
    const int b = blockIdx.y, g = blockIdx.x, tid = threadIdx.x;
    if (tid < 128) w[tid] = sc[b * 128 + tid];
    __syncthreads();
    const int e = g * 256 + tid;
    float acc = 0.f;
    for (int i = 0; i < 128; ++i)
        acc += w[i] * mats[(size_t)(4096 + b * 128 + i) * 2304 + e];
    mixed[(size_t)b * 2304 + e] = acc;
}

// ---------------------------------------------------------------------------
// expm via scaling-squaring Taylor (s=2, degree 12). One block per b.
// ---------------------------------------------------------------------------
__global__ __launch_bounds__(256) void expm_kernel(const float* __restrict__ mixed,
                                                   float* __restrict__ out)
{
    __shared__ float Bs[48][49];
    __shared__ float Ra[48][49];
    __shared__ float Rb[48][49];
    const int b = blockIdx.x, tid = threadIdx.x;
    const float* M = mixed + (size_t)b * 2304;
    for (int e = tid; e < 2304; e += 256) {
        int r = e / 48, c = e % 48;
        float v = 0.25f * M[e];
        Bs[r][c] = v;
        Ra[r][c] = ((r == c) ? 1.f : 0.f) + v * (1.f / 12.f);
    }
    __syncthreads();
    const int tr = tid >> 4, tc = tid & 15;
    const int r0 = tr * 3, c0 = tc * 3;
    float* cur = &Ra[0][0];
    float* nxt = &Rb[0][0];
    for (int k = 11; k >= 1; --k) {
        const float invk = 1.f / (float)k;
        float acc[3][3];
        #pragma unroll
        for (int i = 0; i < 3; ++i)
            #pragma unroll
            for (int j = 0; j < 3; ++j) acc[i][j] = 0.f;
        #pragma unroll 4
        for (int kk = 0; kk < 48; ++kk) {
            float a0 = Bs[r0][kk], a1 = Bs[r0 + 1][kk], a2 = Bs[r0 + 2][kk];
            float b0 = cur[kk * 49 + c0], b1 = cur[kk * 49 + c0 + 1], b2 = cur[kk * 49 + c0 + 2];
            acc[0][0] += a0 * b0; acc[0][1] += a0 * b1; acc[0][2] += a0 * b2;
            acc[1][0] += a1 * b0; acc[1][1] += a1 * b1; acc[1][2] += a1 * b2;
            acc[2][0] += a2 * b0; acc[2][1] += a2 * b1; acc[2][2] += a2 * b2;
        }
        #pragma unroll
        for (int i = 0; i < 3; ++i)
            #pragma unroll
            for (int j = 0; j < 3; ++j)
                nxt[(r0 + i) * 49 + (c0 + j)] =
                    ((r0 + i) == (c0 + j) ? 1.f : 0.f) + acc[i][j] * invk;
        __syncthreads();
        float* t = cur; cur = nxt; nxt = t;
    }
    for (int sq = 0; sq < 2; ++sq) {
        float acc[3][3];
        #pragma unroll
        for (int i = 0; i < 3; ++i)
            #pragma unroll
            for (int j = 0; j < 3; ++j) acc[i][j] = 0.f;
        #pragma unroll 4
        for (int kk = 0; kk < 48; ++kk) {
            float a0 = cur[(r0) * 49 + kk], a1 = cur[(r0 + 1) * 49 + kk], a2 = cur[(r0 + 2) * 49 + kk];
            float b0 = cur[kk * 49 + c0], b1 = cur[kk * 49 + c0 + 1], b2 = cur[kk * 49 + c0 + 2];
            acc[0][0] += a0 * b0; acc[0][1] += a0 * b1; acc[0][2] += a0 * b2;
            acc[1][0] += a1 * b0; acc[1][1] += a1 * b1; acc[1][2] += a1 * b2;
            acc[2][0] += a2 * b0; acc[2][1] += a2 * b1; acc[2][2] += a2 * b2;
        }
        __syncthreads();
        #pragma unroll
        for (int i = 0; i < 3; ++i)
            #pragma unroll
            for (int j = 0; j < 3; ++j) nxt[(r0 + i) * 49 + (c0 + j)] = acc[i][j];
        __syncthreads();
        float* t = cur; cur = nxt; nxt = t;
    }
    #pragma unroll
    for (int i = 0; i < 3; ++i)
        #pragma unroll
        for (int j = 0; j < 3; ++j)
            out[(size_t)b * 2304 + (r0 + i) * 48 + (c0 + j)] = cur[(r0 + i) * 49 + (c0 + j)];
}

// ---------------------------------------------------------------------------
extern "C" void kernel_launch(void* const* d_in, const int* in_sizes, int n_in,
                              void* d_out, int out_size, void* d_ws, size_t ws_size,
                              hipStream_t stream)
{
    (void)in_sizes; (void)n_in; (void)out_size; (void)ws_size;
    const float* x1  = (const float*)d_in[0];
    const float* x2  = (const float*)d_in[1];
    const float* wk1 = (const float*)d_in[3];
    const float* wv1 = (const float*)d_in[4];
    const float* wq2 = (const float*)d_in[5];
    const float* wk2 = (const float*)d_in[6];
    const float* wv2 = (const float*)d_in[7];
    float* mats  = (float*)d_ws;                        // [8224][2304]
    float* mixed = mats + (size_t)8224 * 2304;          // [32][2304]
    float* wtbuf = mixed + (size_t)32 * 2304;           // [5][96*48]
    float* scbuf = wtbuf + (size_t)5 * 4608;            // [32][128]
    float* out   = (float*)d_out;

    Cheb co;
    {
        const double a = 0.098, bb = 5.5;
        const int N = 256;
        for (int k = 0; k <= D_CHEB; ++k) {
            double sacc = 0.0;
            for (int j = 0; j < N; ++j) {
                double th = M_PI * (j + 0.5) / N;
                double xj = 0.5 * (a + bb) + 0.5 * (bb - a) * cos(th);
                sacc += log(xj) * cos(k * th);
            }
            double ck = 2.0 * sacc / N;
            if (k == 0) ck *= 0.5;
            co.c[k] = (float)ck;
        }
        co.sm  = (float)(4.0 / (bb - a));
        co.sbd = (float)((4.0 * 1e-6 - 2.0 * (a + bb)) / (bb - a));
    }

    transpose_w<<<5, 256, 0, stream>>>(wk1, wv1, wk2, wv2, wq2, wtbuf);
    bimap_kernel<<<4128, 64, 0, stream>>>(x1, x2, wtbuf, mats);
    logm_kernel<<<8224, 64, 0, stream>>>(mats, co);
    energy_kernel<<<dim3(128, 32), 64, 0, stream>>>(mats, scbuf);
    softmax_kernel<<<32, 64, 0, stream>>>(scbuf);
    mix_kernel<<<dim3(9, 32), 256, 0, stream>>>(mats, scbuf, mixed);
    expm_kernel<<<32, 256, 0, stream>>>(mixed, out);
}

// Round 3
// 576.503 us; speedup vs baseline: 3.3428x; 1.6643x over previous
//
#include <hip/hip_runtime.h>
#include <math.h>

#define D_CHEB 24
#define TPAD 52   // row pad for Tt (96x48) in bimap

typedef __attribute__((ext_vector_type(8))) short bf16x8;
typedef __attribute__((ext_vector_type(4))) float f32x4;
typedef __attribute__((ext_vector_type(4))) unsigned int u32x4;

struct Cheb {
    float c[D_CHEB + 1];  // c[1..D] pre-halved on host (b' = 0.5 b trick)
    float sm;   // S2 = sm*A + sbd*I
    float sbd;
};

// load 6 consecutive floats (8B-aligned) as 3 float2 into dst[0..5]
#define LD6(dst, base, off) {                                   \
    float2 _t0 = *(const float2*)((base) + (off));              \
    float2 _t1 = *(const float2*)((base) + (off) + 2);          \
    float2 _t2 = *(const float2*)((base) + (off) + 4);          \
    dst[0]=_t0.x; dst[1]=_t0.y; dst[2]=_t1.x;                   \
    dst[3]=_t1.y; dst[4]=_t2.x; dst[5]=_t2.y; }

// ---------------------------------------------------------------------------
// transpose W (48x96 row-major) -> Wt (96x48), 5 matrices
// ---------------------------------------------------------------------------
__global__ __launch_bounds__(256) void transpose_w(
    const float* __restrict__ w0, const float* __restrict__ w1,
    const float* __restrict__ w2, const float* __restrict__ w3,
    const float* __restrict__ w4, float* __restrict__ wt)
{
    const float* W = (blockIdx.x == 0) ? w0 : (blockIdx.x == 1) ? w1
                   : (blockIdx.x == 2) ? w2 : (blockIdx.x == 3) ? w3 : w4;
    float* D = wt + blockIdx.x * 4608;
    for (int e = threadIdx.x; e < 4608; e += 256)
        D[(e % 96) * 48 + e / 96] = W[e];
}

// ---------------------------------------------------------------------------
// bimap: one wave per matrix(-pair). bid<4096: K and V. bid>=4096: Q.
// mats: [0..4095] K (b*128+s*64+m), [4096..8191] V, [8192..8223] Q
// ---------------------------------------------------------------------------
__global__ __launch_bounds__(64, 2) void bimap_kernel(
    const float* __restrict__ x1, const float* __restrict__ x2,
    const float* __restrict__ wt, float* __restrict__ mats)
{
    __shared__ float Tt[96 * TPAD];  // T transposed: Tt[c][r], c<96, r<48
    const int bid = blockIdx.x, tid = threadIdx.x;
    const int ty = tid >> 3, tx = tid & 7;
    const int r0 = ty * 6;

    const float* x; const float* W[2]; size_t oo[2]; int npass;
    if (bid < 4096) {
        int b = bid >> 7, s = (bid >> 6) & 1, m = bid & 63;
        x = (s ? x2 : x1) + (size_t)(b * 64 + m) * 9216;
        W[0] = wt + (s ? 2 : 0) * 4608;  // wk
        W[1] = wt + (s ? 3 : 1) * 4608;  // wv
        oo[0] = (size_t)bid; oo[1] = (size_t)(4096 + bid); npass = 2;
    } else {
        int b = bid - 4096;
        x = x2 + (size_t)(b * 64 + 63) * 9216;
        W[0] = wt + 4 * 4608; W[1] = W[0];
        oo[0] = (size_t)(8192 + b); oo[1] = oo[0]; npass = 1;
    }

    for (int pass = 0; pass < npass; ++pass) {
        const float* Wt = W[pass];
        // phase 1: T = W @ x ; tile 6 rows x 12 cols per lane
        const int cx = tx * 12;
        {
            float acc[6][12];
            #pragma unroll
            for (int i = 0; i < 6; ++i)
                #pragma unroll
                for (int j = 0; j < 12; ++j) acc[i][j] = 0.f;
            #pragma unroll 4
            for (int kk = 0; kk < 96; ++kk) {
                float a[6];
                LD6(a, Wt, kk * 48 + r0);
                float4 b0 = *(const float4*)(x + kk * 96 + cx);
                float4 b1 = *(const float4*)(x + kk * 96 + cx + 4);
                float4 b2 = *(const float4*)(x + kk * 96 + cx + 8);
                float b[12] = {b0.x,b0.y,b0.z,b0.w, b1.x,b1.y,b1.z,b1.w,
                               b2.x,b2.y,b2.z,b2.w};
                #pragma unroll
                for (int i = 0; i < 6; ++i)
                    #pragma unroll
                    for (int j = 0; j < 12; ++j)
                        acc[i][j] = fmaf(a[i], b[j], acc[i][j]);
            }
            #pragma unroll
            for (int i = 0; i < 6; ++i)
                #pragma unroll
                for (int j = 0; j < 12; ++j)
                    Tt[(cx + j) * TPAD + r0 + i] = acc[i][j];
        }
        // phase 2: out = T @ W^T ; tile 6x6 per lane
        {
            const int p0 = tx * 6;
            float acc[6][6];
            #pragma unroll
            for (int i = 0; i < 6; ++i)
                #pragma unroll
                for (int j = 0; j < 6; ++j) acc[i][j] = 0.f;
            #pragma unroll 8
            for (int j = 0; j < 96; ++j) {
                float a[6], b[6];
                LD6(a, Tt, j * TPAD + r0);
                LD6(b, Wt, j * 48 + p0);
                #pragma unroll
                for (int i = 0; i < 6; ++i)
                    #pragma unroll
                    for (int jj = 0; jj < 6; ++jj)
                        acc[i][jj] = fmaf(a[i], b[jj], acc[i][jj]);
            }
            float* out = mats + oo[pass] * 2304;
            #pragma unroll
            for (int i = 0; i < 6; ++i)
                #pragma unroll
                for (int q = 0; q < 3; ++q)
                    *(float2*)(out + (r0 + i) * 48 + p0 + 2 * q) =
                        make_float2(acc[i][2 * q], acc[i][2 * q + 1]);
        }
    }
}

// ---------------------------------------------------------------------------
// logm: Chebyshev-Clenshaw via split-bf16 MFMA. One wave per matrix, in-place.
// Exploits symmetry of S2 and all Clenshaw iterates: both MFMA operands are
// row-major contiguous reads. LDS holds bf16 hi/lo split of the current Y,
// XOR-swizzled (byte ^= (row&7)<<4 within the 128B row).
// ---------------------------------------------------------------------------
__global__ __launch_bounds__(64, 3) void logm_kernel(float* __restrict__ mats, Cheb co)
{
    __shared__ __align__(16) unsigned short Ybuf[2 * 48 * 64];  // hi @0, lo @+6144B
    char* ldsb = (char*)Ybuf;
    const int l = threadIdx.x;
    const int lc = l & 15, lg = l >> 4;
    const int rloc = lg * 4;
    float* A = mats + (size_t)blockIdx.x * 2304;

    // ---- A-frags (S2 split) in registers + seed LDS with split(b'_{D-1}) ----
    bf16x8 Ah[3][2], Al[3][2];
    const float cD = co.c[D_CHEB], cD1 = co.c[D_CHEB - 1];
    #pragma unroll
    for (int tr = 0; tr < 3; ++tr) {
        #pragma unroll
        for (int kb = 0; kb < 2; ++kb) {
            const int row = 16 * tr + lc;
            const int k0 = kb * 32 + lg * 8;
            unsigned shw[4] = {0,0,0,0}, slw[4] = {0,0,0,0};
            unsigned yhw[4] = {0,0,0,0}, ylw[4] = {0,0,0,0};
            if (k0 < 48) {
                const float* ap = A + row * 48 + k0;
                f32x4 a0 = *(const f32x4*)ap;
                f32x4 a1 = *(const f32x4*)(ap + 4);
                float av[8] = {a0[0],a0[1],a0[2],a0[3],a1[0],a1[1],a1[2],a1[3]};
                unsigned sh[8], sl[8], yh[8], yl[8];
                #pragma unroll
                for (int j = 0; j < 8; ++j) {
                    const bool diag = (row == k0 + j);
                    float s = co.sm * av[j] + (diag ? co.sbd : 0.f);
                    float y = cD * s + (diag ? cD1 : 0.f);
                    unsigned us = __float_as_uint(s);
                    sh[j] = us >> 16;
                    sl[j] = __float_as_uint(s - __uint_as_float(us & 0xFFFF0000u)) >> 16;
                    unsigned uy = __float_as_uint(y);
                    yh[j] = uy >> 16;
                    yl[j] = __float_as_uint(y - __uint_as_float(uy & 0xFFFF0000u)) >> 16;
                }
                #pragma unroll
                for (int q = 0; q < 4; ++q) {
                    shw[q] = sh[2*q] | (sh[2*q+1] << 16);
                    slw[q] = sl[2*q] | (sl[2*q+1] << 16);
                    yhw[q] = yh[2*q] | (yh[2*q+1] << 16);
                    ylw[q] = yl[2*q] | (yl[2*q+1] << 16);
                }
            }
            Ah[tr][kb] = __builtin_bit_cast(bf16x8, (u32x4){shw[0],shw[1],shw[2],shw[3]});
            Al[tr][kb] = __builtin_bit_cast(bf16x8, (u32x4){slw[0],slw[1],slw[2],slw[3]});
            const int soff = row * 128 + ((2 * k0) ^ ((row & 7) << 4));
            *(u32x4*)(ldsb + soff)        = (u32x4){yhw[0],yhw[1],yhw[2],yhw[3]};
            *(u32x4*)(ldsb + 6144 + soff) = (u32x4){ylw[0],ylw[1],ylw[2],ylw[3]};
        }
    }

    // ---- seed C-layout registers: Ya = b'_{D-1} = cD1*I + cD*S2 ; Yb = cD*I
    f32x4 Ya[9], Yb[9];
    #pragma unroll
    for (int t = 0; t < 9; ++t) {
        const int tr = t / 3, tc = t % 3;
        #pragma unroll
        for (int q = 0; q < 4; ++q) {
            const int row = 16 * tr + rloc + q, col = 16 * tc + lc;
            const bool diag = (row == col);
            float a = A[row * 48 + col];
            float s = co.sm * a + (diag ? co.sbd : 0.f);
            Ya[t][q] = cD * s + (diag ? cD1 : 0.f);
            Yb[t][q] = diag ? cD : 0.f;
        }
    }

    // ---- precomputed per-lane LDS byte offsets ----
    int boff[3][2];   // B-frag reads: row = 16tc+lc, chunk kb*64 + lg*16
    #pragma unroll
    for (int tc = 0; tc < 3; ++tc)
        #pragma unroll
        for (int kb = 0; kb < 2; ++kb) {
            const int row = 16 * tc + lc;
            boff[tc][kb] = row * 128 + ((kb * 64 + lg * 16) ^ ((row & 7) << 4));
        }
    int woff[3][4];   // scatter writes: row = 16tr+rloc+q (tr via +2048 imm)
    #pragma unroll
    for (int tc = 0; tc < 3; ++tc)
        #pragma unroll
        for (int q = 0; q < 4; ++q) {
            const int rq = rloc + q;
            woff[tc][q] = rq * 128 + ((32 * tc + 2 * lc) ^ ((rq & 7) << 4));
        }

    auto MM = [&](f32x4 (&T)[9]) {
        #pragma unroll
        for (int tc = 0; tc < 3; ++tc) {
            #pragma unroll
            for (int kb = 0; kb < 2; ++kb) {
                bf16x8 bh = *(const bf16x8*)(ldsb + boff[tc][kb]);
                bf16x8 bl = *(const bf16x8*)(ldsb + 6144 + boff[tc][kb]);
                #pragma unroll
                for (int tr = 0; tr < 3; ++tr) {
                    T[tr*3+tc] = __builtin_amdgcn_mfma_f32_16x16x32_bf16(Ah[tr][kb], bh, T[tr*3+tc], 0, 0, 0);
                    T[tr*3+tc] = __builtin_amdgcn_mfma_f32_16x16x32_bf16(Ah[tr][kb], bl, T[tr*3+tc], 0, 0, 0);
                    T[tr*3+tc] = __builtin_amdgcn_mfma_f32_16x16x32_bf16(Al[tr][kb], bh, T[tr*3+tc], 0, 0, 0);
                }
            }
        }
    };
    auto SPLITW = [&](f32x4 (&T)[9]) {
        #pragma unroll
        for (int t = 0; t < 9; ++t) {
            const int tr = t / 3, tc = t % 3;
            #pragma unroll
            for (int q = 0; q < 4; ++q) {
                float v = T[t][q];
                unsigned u = __float_as_uint(v);
                unsigned lo = __float_as_uint(v - __uint_as_float(u & 0xFFFF0000u)) >> 16;
                const int off = tr * 2048 + woff[tc][q];
                *(unsigned short*)(ldsb + off) = (unsigned short)(u >> 16);
                *(unsigned short*)(ldsb + 6144 + off) = (unsigned short)lo;
            }
        }
    };
    auto INITK = [&](f32x4 (&T)[9], float ck) {
        #pragma unroll
        for (int t = 0; t < 9; ++t) {
            const int tr = t / 3, tc = t % 3;
            #pragma unroll
            for (int q = 0; q < 4; ++q) {
                const float d = (tr == tc && rloc + q == lc) ? ck : 0.f;
                T[t][q] = d - T[t][q];
            }
        }
    };

    // ---- Clenshaw: b'_k = c'_k I − b'_{k+2} + S2 @ b'_{k+1} ----
    for (int k = D_CHEB - 2; k >= 2; k -= 2) {
        INITK(Yb, co.c[k]);     MM(Yb);  SPLITW(Yb);
        INITK(Ya, co.c[k - 1]); MM(Ya);  SPLITW(Ya);
    }
    // ---- final: log = c0 I − 2 b'_2 + S2 @ b'_1  (b'_1 split is in LDS) ----
    #pragma unroll
    for (int t = 0; t < 9; ++t) {
        const int tr = t / 3, tc = t % 3;
        #pragma unroll
        for (int q = 0; q < 4; ++q) {
            const float d = (tr == tc && rloc + q == lc) ? co.c[0] : 0.f;
            Yb[t][q] = d - 2.f * Yb[t][q];
        }
    }
    MM(Yb);
    #pragma unroll
    for (int t = 0; t < 9; ++t) {
        const int tr = t / 3, tc = t % 3;
        #pragma unroll
        for (int q = 0; q < 4; ++q)
            A[(16 * tr + rloc + q) * 48 + 16 * tc + lc] = Yb[t][q];
    }
}

// ---------------------------------------------------------------------------
// attention, split: energy (4096 waves) -> softmax (32 waves) -> mix (288 blk)
// ---------------------------------------------------------------------------
__global__ __launch_bounds__(64) void energy_kernel(const float* __restrict__ mats,
                                                    float* __restrict__ sc)
{
    const int i = blockIdx.x, b = blockIdx.y, lane = threadIdx.x;
    const float* K = mats + (size_t)(b * 128 + i) * 2304;
    const float* Q = mats + (size_t)(8192 + b) * 2304;
    float p = 0.f;
    #pragma unroll
    for (int j = 0; j < 9; ++j) {
        int f = (lane + 64 * j) * 4;
        float4 kv = *(const float4*)(K + f);
        float4 qv = *(const float4*)(Q + f);
        float dx = kv.x - qv.x, dy = kv.y - qv.y, dz = kv.z - qv.z, dw = kv.w - qv.w;
        p += dx * dx + dy * dy + dz * dz + dw * dw;
    }
    #pragma unroll
    for (int off = 32; off >= 1; off >>= 1) p += __shfl_xor(p, off, 64);
    if (lane == 0)
        sc[b * 128 + i] = 1.f / (1.f + log1pf(fmaxf(p, 0.f)));
}

__global__ __launch_bounds__(64) void softmax_kernel(float* __restrict__ sc)
{
    const int b = blockIdx.x, lane = threadIdx.x;
    float s0 = sc[b * 128 + lane], s1 = sc[b * 128 + 64 + lane];
    float m = fmaxf(s0, s1);
    #pragma unroll
    for (int off = 32; off >= 1; off >>= 1) m = fmaxf(m, __shfl_xor(m, off, 64));
    float e0 = expf(s0 - m), e1 = expf(s1 - m);
    float sum = e0 + e1;
    #pragma unroll
    for (int off = 32; off >= 1; off >>= 1) sum += __shfl_xor(sum, off, 64);
    sc[b * 128 + lane] = e0 / sum;
    sc[b * 128 + 64 + lane] = e1 / sum;
}

__global__ __launch_bounds__(256) void mix_kernel(const float* __restrict__ mats,
                                                  const float* __restrict__ sc,
                                                  float* __restrict__ mixed)
{
    __shared__ float w[128];
    const int b = blockIdx.y, g = blockIdx.x, tid = threadIdx.x;
    if (tid < 128) w[tid] = sc[b * 128 + tid];
    __syncthreads();
    const int e = g * 256 + tid;
    float acc = 0.f;
    for (int i = 0; i < 128; ++i)
        acc += w[i] * mats[(size_t)(4096 + b * 128 + i) * 2304 + e];
    mixed[(size_t)b * 2304 + e] = acc;
}

// ---------------------------------------------------------------------------
// expm via scaling-squaring Taylor (s=2, degree 12). One block per b.
// ---------------------------------------------------------------------------
__global__ __launch_bounds__(256) void expm_kernel(const float* __restrict__ mixed,
                                                   float* __restrict__ out)
{
    __shared__ float Bs[48][49];
    __shared__ float Ra[48][49];
    __shared__ float Rb[48][49];
    const int b = blockIdx.x, tid = threadIdx.x;
    const float* M = mixed + (size_t)b * 2304;
    for (int e = tid; e < 2304; e += 256) {
        int r = e / 48, c = e % 48;
        float v = 0.25f * M[e];
        Bs[r][c] = v;
        Ra[r][c] = ((r == c) ? 1.f : 0.f) + v * (1.f / 12.f);
    }
    __syncthreads();
    const int tr = tid >> 4, tc = tid & 15;
    const int r0 = tr * 3, c0 = tc * 3;
    float* cur = &Ra[0][0];
    float* nxt = &Rb[0][0];
    for (int k = 11; k >= 1; --k) {
        const float invk = 1.f / (float)k;
        float acc[3][3];
        #pragma unroll
        for (int i = 0; i < 3; ++i)
            #pragma unroll
            for (int j = 0; j < 3; ++j) acc[i][j] = 0.f;
        #pragma unroll 4
        for (int kk = 0; kk < 48; ++kk) {
            float a0 = Bs[r0][kk], a1 = Bs[r0 + 1][kk], a2 = Bs[r0 + 2][kk];
            float b0 = cur[kk * 49 + c0], b1 = cur[kk * 49 + c0 + 1], b2 = cur[kk * 49 + c0 + 2];
            acc[0][0] += a0 * b0; acc[0][1] += a0 * b1; acc[0][2] += a0 * b2;
            acc[1][0] += a1 * b0; acc[1][1] += a1 * b1; acc[1][2] += a1 * b2;
            acc[2][0] += a2 * b0; acc[2][1] += a2 * b1; acc[2][2] += a2 * b2;
        }
        #pragma unroll
        for (int i = 0; i < 3; ++i)
            #pragma unroll
            for (int j = 0; j < 3; ++j)
                nxt[(r0 + i) * 49 + (c0 + j)] =
                    ((r0 + i) == (c0 + j) ? 1.f : 0.f) + acc[i][j] * invk;
        __syncthreads();
        float* t = cur; cur = nxt; nxt = t;
    }
    for (int sq = 0; sq < 2; ++sq) {
        float acc[3][3];
        #pragma unroll
        for (int i = 0; i < 3; ++i)
            #pragma unroll
            for (int j = 0; j < 3; ++j) acc[i][j] = 0.f;
        #pragma unroll 4
        for (int kk = 0; kk < 48; ++kk) {
            float a0 = cur[(r0) * 49 + kk], a1 = cur[(r0 + 1) * 49 + kk], a2 = cur[(r0 + 2) * 49 + kk];
            float b0 = cur[kk * 49 + c0], b1 = cur[kk * 49 + c0 + 1], b2 = cur[kk * 49 + c0 + 2];
            acc[0][0] += a0 * b0; acc[0][1] += a0 * b1; acc[0][2] += a0 * b2;
            acc[1][0] += a1 * b0; acc[1][1] += a1 * b1; acc[1][2] += a1 * b2;
            acc[2][0] += a2 * b0; acc[2][1] += a2 * b1; acc[2][2] += a2 * b2;
        }
        __syncthreads();
        #pragma unroll
        for (int i = 0; i < 3; ++i)
            #pragma unroll
            for (int j = 0; j < 3; ++j) nxt[(r0 + i) * 49 + (c0 + j)] = acc[i][j];
        __syncthreads();
        float* t = cur; cur = nxt; nxt = t;
    }
    #pragma unroll
    for (int i = 0; i < 3; ++i)
        #pragma unroll
        for (int j = 0; j < 3; ++j)
            out[(size_t)b * 2304 + (r0 + i) * 48 + (c0 + j)] = cur[(r0 + i) * 49 + (c0 + j)];
}

// ---------------------------------------------------------------------------
extern "C" void kernel_launch(void* const* d_in, const int* in_sizes, int n_in,
                              void* d_out, int out_size, void* d_ws, size_t ws_size,
                              hipStream_t stream)
{
    (void)in_sizes; (void)n_in; (void)out_size; (void)ws_size;
    const float* x1  = (const float*)d_in[0];
    const float* x2  = (const float*)d_in[1];
    const float* wk1 = (const float*)d_in[3];
    const float* wv1 = (const float*)d_in[4];
    const float* wq2 = (const float*)d_in[5];
    const float* wk2 = (const float*)d_in[6];
    const float* wv2 = (const float*)d_in[7];
    float* mats  = (float*)d_ws;                        // [8224][2304]
    float* mixed = mats + (size_t)8224 * 2304;          // [32][2304]
    float* wtbuf = mixed + (size_t)32 * 2304;           // [5][96*48]
    float* scbuf = wtbuf + (size_t)5 * 4608;            // [32][128]
    float* out   = (float*)d_out;

    Cheb co;
    {
        const double a = 0.098, bb = 5.5;
        const int N = 256;
        for (int k = 0; k <= D_CHEB; ++k) {
            double sacc = 0.0;
            for (int j = 0; j < N; ++j) {
                double th = M_PI * (j + 0.5) / N;
                double xj = 0.5 * (a + bb) + 0.5 * (bb - a) * cos(th);
                sacc += log(xj) * cos(k * th);
            }
            double ck = 2.0 * sacc / N;
            if (k == 0) ck *= 0.5;
            if (k >= 1) ck *= 0.5;   // fold the final 0.5*S2 into all iterates
            co.c[k] = (float)ck;
        }
        co.sm  = (float)(4.0 / (bb - a));
        co.sbd = (float)((4.0 * 1e-6 - 2.0 * (a + bb)) / (bb - a));
    }

    transpose_w<<<5, 256, 0, stream>>>(wk1, wv1, wk2, wv2, wq2, wtbuf);
    bimap_kernel<<<4128, 64, 0, stream>>>(x1, x2, wtbuf, mats);
    logm_kernel<<<8224, 64, 0, stream>>>(mats, co);
    energy_kernel<<<dim3(128, 32), 64, 0, stream>>>(mats, scbuf);
    softmax_kernel<<<32, 64, 0, stream>>>(scbuf);
    mix_kernel<<<dim3(9, 32), 256, 0, stream>>>(mats, scbuf, mixed);
    expm_kernel<<<32, 256, 0, stream>>>(mixed, out);
}

// Round 4
// 436.543 us; speedup vs baseline: 4.4145x; 1.3206x over previous
//
#include <hip/hip_runtime.h>
#include <math.h>

#define D_CHEB 24

typedef __attribute__((ext_vector_type(8))) short bf16x8;
typedef __attribute__((ext_vector_type(4))) float f32x4;
typedef __attribute__((ext_vector_type(4))) unsigned int u32x4;

struct Cheb {
    float c[D_CHEB + 1];  // c[1..D] pre-halved on host (b' = 0.5 b trick)
    float sm;   // S2 = sm*A + sbd*I
    float sbd;
};

// split 8 f32 (two f32x4) into bf16 hi (RNE) + lo (trunc of residual)
__device__ __forceinline__ void split8(const f32x4 a, const f32x4 b,
                                       bf16x8& hi, bf16x8& lo)
{
    float v[8] = {a[0], a[1], a[2], a[3], b[0], b[1], b[2], b[3]};
    unsigned h16[8], l16[8];
    #pragma unroll
    for (int j = 0; j < 8; ++j) {
        unsigned u = __float_as_uint(v[j]);
        unsigned r = (u + 0x7FFFu + ((u >> 16) & 1u)) >> 16;   // RNE to bf16
        h16[j] = r;
        float res = v[j] - __uint_as_float(r << 16);
        l16[j] = __float_as_uint(res) >> 16;                    // trunc residual
    }
    unsigned hw[4], lw[4];
    #pragma unroll
    for (int q = 0; q < 4; ++q) {
        hw[q] = h16[2 * q] | (h16[2 * q + 1] << 16);
        lw[q] = l16[2 * q] | (l16[2 * q + 1] << 16);
    }
    hi = __builtin_bit_cast(bf16x8, (u32x4){hw[0], hw[1], hw[2], hw[3]});
    lo = __builtin_bit_cast(bf16x8, (u32x4){lw[0], lw[1], lw[2], lw[3]});
}

// ---------------------------------------------------------------------------
// split W (48x96 row-major f32) -> bf16 hi/lo, 5 matrices
// ---------------------------------------------------------------------------
__global__ __launch_bounds__(256) void split_w(
    const float* __restrict__ w0, const float* __restrict__ w1,
    const float* __restrict__ w2, const float* __restrict__ w3,
    const float* __restrict__ w4,
    unsigned short* __restrict__ whi, unsigned short* __restrict__ wlo)
{
    const float* W = (blockIdx.x == 0) ? w0 : (blockIdx.x == 1) ? w1
                   : (blockIdx.x == 2) ? w2 : (blockIdx.x == 3) ? w3 : w4;
    const int base = blockIdx.x * 4608;
    for (int e = threadIdx.x; e < 4608; e += 256) {
        float f = W[e];
        unsigned u = __float_as_uint(f);
        unsigned r = (u + 0x7FFFu + ((u >> 16) & 1u)) >> 16;
        whi[base + e] = (unsigned short)r;
        float res = f - __uint_as_float(r << 16);
        wlo[base + e] = (unsigned short)(__float_as_uint(res) >> 16);
    }
}

// ---------------------------------------------------------------------------
// bimap via split-bf16 MFMA: out = W x W^T. One wave per matrix(-pair).
// bid<4096: K and V passes. bid>=4096: Q pass.
// phase1: T = W @ x   (A = W rows from global bf16; B = x rows via symmetry)
// phase2: out = T @ W^T (A = T rows from LDS f32+split; B = W rows global)
// mats: [0..4095] K (b*128+s*64+m), [4096..8191] V, [8192..8223] Q
// ---------------------------------------------------------------------------
#define TLP 104   // T row pitch (f32): 104%32=8 -> <=2-way write conflicts
__global__ __launch_bounds__(64, 3) void bimap_kernel(
    const float* __restrict__ x1, const float* __restrict__ x2,
    const unsigned short* __restrict__ whi,
    const unsigned short* __restrict__ wlo,
    float* __restrict__ mats)
{
    __shared__ float Tlds[48 * TLP];
    const int bid = blockIdx.x, l = threadIdx.x;
    const int lc = l & 15, lg = l >> 4;

    const float* x; int wi[2]; size_t oo[2]; int npass;
    if (bid < 4096) {
        int b = bid >> 7, s = (bid >> 6) & 1, m = bid & 63;
        x = (s ? x2 : x1) + (size_t)(b * 64 + m) * 9216;
        wi[0] = s ? 2 : 0;  // wk
        wi[1] = s ? 3 : 1;  // wv
        oo[0] = (size_t)bid; oo[1] = (size_t)(4096 + bid); npass = 2;
    } else {
        int b = bid - 4096;
        x = x2 + (size_t)(b * 64 + 63) * 9216;
        wi[0] = 4; wi[1] = 4;
        oo[0] = (size_t)(8192 + b); oo[1] = oo[0]; npass = 1;
    }

    for (int pass = 0; pass < npass; ++pass) {
        const unsigned short* Wh = whi + wi[pass] * 4608;
        const unsigned short* Wl = wlo + wi[pass] * 4608;

        // ---- phase 1: T(48x96) = W @ x, K=96 ----
        f32x4 C[3][6];
        #pragma unroll
        for (int tr = 0; tr < 3; ++tr)
            #pragma unroll
            for (int tc = 0; tc < 6; ++tc)
                C[tr][tc] = (f32x4){0.f, 0.f, 0.f, 0.f};
        #pragma unroll
        for (int kb = 0; kb < 3; ++kb) {
            bf16x8 ah[3], al[3];
            #pragma unroll
            for (int tr = 0; tr < 3; ++tr) {
                const int off = (16 * tr + lc) * 96 + kb * 32 + lg * 8;
                ah[tr] = *(const bf16x8*)(Wh + off);
                al[tr] = *(const bf16x8*)(Wl + off);
            }
            #pragma unroll
            for (int tc = 0; tc < 6; ++tc) {
                const float* xp = x + (16 * tc + lc) * 96 + kb * 32 + lg * 8;
                bf16x8 bh, bl;
                split8(*(const f32x4*)xp, *(const f32x4*)(xp + 4), bh, bl);
                #pragma unroll
                for (int tr = 0; tr < 3; ++tr) {
                    C[tr][tc] = __builtin_amdgcn_mfma_f32_16x16x32_bf16(ah[tr], bh, C[tr][tc], 0, 0, 0);
                    C[tr][tc] = __builtin_amdgcn_mfma_f32_16x16x32_bf16(ah[tr], bl, C[tr][tc], 0, 0, 0);
                    C[tr][tc] = __builtin_amdgcn_mfma_f32_16x16x32_bf16(al[tr], bh, C[tr][tc], 0, 0, 0);
                }
            }
        }
        // T -> LDS (f32, row-major, pitch TLP)
        #pragma unroll
        for (int tr = 0; tr < 3; ++tr)
            #pragma unroll
            for (int tc = 0; tc < 6; ++tc)
                #pragma unroll
                for (int q = 0; q < 4; ++q)
                    Tlds[(16 * tr + 4 * lg + q) * TLP + 16 * tc + lc] = C[tr][tc][q];

        // ---- phase 2: out(48x48) = T @ W^T, K=96 ----
        f32x4 D[3][3];
        #pragma unroll
        for (int tr = 0; tr < 3; ++tr)
            #pragma unroll
            for (int tc = 0; tc < 3; ++tc)
                D[tr][tc] = (f32x4){0.f, 0.f, 0.f, 0.f};
        #pragma unroll
        for (int kb = 0; kb < 3; ++kb) {
            bf16x8 ah[3], al[3];
            #pragma unroll
            for (int tr = 0; tr < 3; ++tr) {
                const float* tp = &Tlds[(16 * tr + lc) * TLP + kb * 32 + lg * 8];
                split8(*(const f32x4*)tp, *(const f32x4*)(tp + 4), ah[tr], al[tr]);
            }
            #pragma unroll
            for (int tc = 0; tc < 3; ++tc) {
                const int off = (16 * tc + lc) * 96 + kb * 32 + lg * 8;
                bf16x8 bh = *(const bf16x8*)(Wh + off);
                bf16x8 bl = *(const bf16x8*)(Wl + off);
                #pragma unroll
                for (int tr = 0; tr < 3; ++tr) {
                    D[tr][tc] = __builtin_amdgcn_mfma_f32_16x16x32_bf16(ah[tr], bh, D[tr][tc], 0, 0, 0);
                    D[tr][tc] = __builtin_amdgcn_mfma_f32_16x16x32_bf16(ah[tr], bl, D[tr][tc], 0, 0, 0);
                    D[tr][tc] = __builtin_amdgcn_mfma_f32_16x16x32_bf16(al[tr], bh, D[tr][tc], 0, 0, 0);
                }
            }
        }
        float* out = mats + oo[pass] * 2304;
        #pragma unroll
        for (int tr = 0; tr < 3; ++tr)
            #pragma unroll
            for (int tc = 0; tc < 3; ++tc)
                #pragma unroll
                for (int q = 0; q < 4; ++q)
                    out[(16 * tr + 4 * lg + q) * 48 + 16 * tc + lc] = D[tr][tc][q];
    }
}

// ---------------------------------------------------------------------------
// logm: Chebyshev-Clenshaw via split-bf16 MFMA. One wave per matrix, in-place.
// ---------------------------------------------------------------------------
__global__ __launch_bounds__(64, 3) void logm_kernel(float* __restrict__ mats, Cheb co)
{
    __shared__ __align__(16) unsigned short Ybuf[2 * 48 * 64];  // hi @0, lo @+6144B
    char* ldsb = (char*)Ybuf;
    const int l = threadIdx.x;
    const int lc = l & 15, lg = l >> 4;
    const int rloc = lg * 4;
    float* A = mats + (size_t)blockIdx.x * 2304;

    // ---- A-frags (S2 split) in registers + seed LDS with split(b'_{D-1}) ----
    bf16x8 Ah[3][2], Al[3][2];
    const float cD = co.c[D_CHEB], cD1 = co.c[D_CHEB - 1];
    #pragma unroll
    for (int tr = 0; tr < 3; ++tr) {
        #pragma unroll
        for (int kb = 0; kb < 2; ++kb) {
            const int row = 16 * tr + lc;
            const int k0 = kb * 32 + lg * 8;
            unsigned shw[4] = {0,0,0,0}, slw[4] = {0,0,0,0};
            unsigned yhw[4] = {0,0,0,0}, ylw[4] = {0,0,0,0};
            if (k0 < 48) {
                const float* ap = A + row * 48 + k0;
                f32x4 a0 = *(const f32x4*)ap;
                f32x4 a1 = *(const f32x4*)(ap + 4);
                float av[8] = {a0[0],a0[1],a0[2],a0[3],a1[0],a1[1],a1[2],a1[3]};
                unsigned sh[8], sl[8], yh[8], yl[8];
                #pragma unroll
                for (int j = 0; j < 8; ++j) {
                    const bool diag = (row == k0 + j);
                    float s = co.sm * av[j] + (diag ? co.sbd : 0.f);
                    float y = cD * s + (diag ? cD1 : 0.f);
                    unsigned us = __float_as_uint(s);
                    sh[j] = us >> 16;
                    sl[j] = __float_as_uint(s - __uint_as_float(us & 0xFFFF0000u)) >> 16;
                    unsigned uy = __float_as_uint(y);
                    yh[j] = uy >> 16;
                    yl[j] = __float_as_uint(y - __uint_as_float(uy & 0xFFFF0000u)) >> 16;
                }
                #pragma unroll
                for (int q = 0; q < 4; ++q) {
                    shw[q] = sh[2*q] | (sh[2*q+1] << 16);
                    slw[q] = sl[2*q] | (sl[2*q+1] << 16);
                    yhw[q] = yh[2*q] | (yh[2*q+1] << 16);
                    ylw[q] = yl[2*q] | (yl[2*q+1] << 16);
                }
            }
            Ah[tr][kb] = __builtin_bit_cast(bf16x8, (u32x4){shw[0],shw[1],shw[2],shw[3]});
            Al[tr][kb] = __builtin_bit_cast(bf16x8, (u32x4){slw[0],slw[1],slw[2],slw[3]});
            const int soff = row * 128 + ((2 * k0) ^ ((row & 7) << 4));
            *(u32x4*)(ldsb + soff)        = (u32x4){yhw[0],yhw[1],yhw[2],yhw[3]};
            *(u32x4*)(ldsb + 6144 + soff) = (u32x4){ylw[0],ylw[1],ylw[2],ylw[3]};
        }
    }

    // ---- seed C-layout registers: Ya = b'_{D-1} = cD1*I + cD*S2 ; Yb = cD*I
    f32x4 Ya[9], Yb[9];
    #pragma unroll
    for (int t = 0; t < 9; ++t) {
        const int tr = t / 3, tc = t % 3;
        #pragma unroll
        for (int q = 0; q < 4; ++q) {
            const int row = 16 * tr + rloc + q, col = 16 * tc + lc;
            const bool diag = (row == col);
            float a = A[row * 48 + col];
            float s = co.sm * a + (diag ? co.sbd : 0.f);
            Ya[t][q] = cD * s + (diag ? cD1 : 0.f);
            Yb[t][q] = diag ? cD : 0.f;
        }
    }

    // ---- precomputed per-lane LDS byte offsets ----
    int boff[3][2];   // B-frag reads: row = 16tc+lc, chunk kb*64 + lg*16
    #pragma unroll
    for (int tc = 0; tc < 3; ++tc)
        #pragma unroll
        for (int kb = 0; kb < 2; ++kb) {
            const int row = 16 * tc + lc;
            boff[tc][kb] = row * 128 + ((kb * 64 + lg * 16) ^ ((row & 7) << 4));
        }
    int woff[3][4];   // scatter writes: row = 16tr+rloc+q (tr via +2048 imm)
    #pragma unroll
    for (int tc = 0; tc < 3; ++tc)
        #pragma unroll
        for (int q = 0; q < 4; ++q) {
            const int rq = rloc + q;
            woff[tc][q] = rq * 128 + ((32 * tc + 2 * lc) ^ ((rq & 7) << 4));
        }

    auto MM = [&](f32x4 (&T)[9]) {
        #pragma unroll
        for (int tc = 0; tc < 3; ++tc) {
            #pragma unroll
            for (int kb = 0; kb < 2; ++kb) {
                bf16x8 bh = *(const bf16x8*)(ldsb + boff[tc][kb]);
                bf16x8 bl = *(const bf16x8*)(ldsb + 6144 + boff[tc][kb]);
                #pragma unroll
                for (int tr = 0; tr < 3; ++tr) {
                    T[tr*3+tc] = __builtin_amdgcn_mfma_f32_16x16x32_bf16(Ah[tr][kb], bh, T[tr*3+tc], 0, 0, 0);
                    T[tr*3+tc] = __builtin_amdgcn_mfma_f32_16x16x32_bf16(Ah[tr][kb], bl, T[tr*3+tc], 0, 0, 0);
                    T[tr*3+tc] = __builtin_amdgcn_mfma_f32_16x16x32_bf16(Al[tr][kb], bh, T[tr*3+tc], 0, 0, 0);
                }
            }
        }
    };
    auto SPLITW = [&](f32x4 (&T)[9]) {
        #pragma unroll
        for (int t = 0; t < 9; ++t) {
            const int tr = t / 3, tc = t % 3;
            #pragma unroll
            for (int q = 0; q < 4; ++q) {
                float v = T[t][q];
                unsigned u = __float_as_uint(v);
                unsigned lo = __float_as_uint(v - __uint_as_float(u & 0xFFFF0000u)) >> 16;
                const int off = tr * 2048 + woff[tc][q];
                *(unsigned short*)(ldsb + off) = (unsigned short)(u >> 16);
                *(unsigned short*)(ldsb + 6144 + off) = (unsigned short)lo;
            }
        }
    };
    auto INITK = [&](f32x4 (&T)[9], float ck) {
        #pragma unroll
        for (int t = 0; t < 9; ++t) {
            const int tr = t / 3, tc = t % 3;
            #pragma unroll
            for (int q = 0; q < 4; ++q) {
                const float d = (tr == tc && rloc + q == lc) ? ck : 0.f;
                T[t][q] = d - T[t][q];
            }
        }
    };

    // ---- Clenshaw: b'_k = c'_k I − b'_{k+2} + S2 @ b'_{k+1} ----
    for (int k = D_CHEB - 2; k >= 2; k -= 2) {
        INITK(Yb, co.c[k]);     MM(Yb);  SPLITW(Yb);
        INITK(Ya, co.c[k - 1]); MM(Ya);  SPLITW(Ya);
    }
    // ---- final: log = c0 I − 2 b'_2 + S2 @ b'_1  (b'_1 split is in LDS) ----
    #pragma unroll
    for (int t = 0; t < 9; ++t) {
        const int tr = t / 3, tc = t % 3;
        #pragma unroll
        for (int q = 0; q < 4; ++q) {
            const float d = (tr == tc && rloc + q == lc) ? co.c[0] : 0.f;
            Yb[t][q] = d - 2.f * Yb[t][q];
        }
    }
    MM(Yb);
    #pragma unroll
    for (int t = 0; t < 9; ++t) {
        const int tr = t / 3, tc = t % 3;
        #pragma unroll
        for (int q = 0; q < 4; ++q)
            A[(16 * tr + rloc + q) * 48 + 16 * tc + lc] = Yb[t][q];
    }
}

// ---------------------------------------------------------------------------
// attention, split: energy (4096 waves) -> softmax (32 waves) -> mix (288 blk)
// ---------------------------------------------------------------------------
__global__ __launch_bounds__(64) void energy_kernel(const float* __restrict__ mats,
                                                    float* __restrict__ sc)
{
    const int i = blockIdx.x, b = blockIdx.y, lane = threadIdx.x;
    const float* K = mats + (size_t)(b * 128 + i) * 2304;
    const float* Q = mats + (size_t)(8192 + b) * 2304;
    float p = 0.f;
    #pragma unroll
    for (int j = 0; j < 9; ++j) {
        int f = (lane + 64 * j) * 4;
        float4 kv = *(const float4*)(K + f);
        float4 qv = *(const float4*)(Q + f);
        float dx = kv.x - qv.x, dy = kv.y - qv.y, dz = kv.z - qv.z, dw = kv.w - qv.w;
        p += dx * dx + dy * dy + dz * dz + dw * dw;
    }
    #pragma unroll
    for (int off = 32; off >= 1; off >>= 1) p += __shfl_xor(p, off, 64);
    if (lane == 0)
        sc[b * 128 + i] = 1.f / (1.f + log1pf(fmaxf(p, 0.f)));
}

__global__ __launch_bounds__(64) void softmax_kernel(float* __restrict__ sc)
{
    const int b = blockIdx.x, lane = threadIdx.x;
    float s0 = sc[b * 128 + lane], s1 = sc[b * 128 + 64 + lane];
    float m = fmaxf(s0, s1);
    #pragma unroll
    for (int off = 32; off >= 1; off >>= 1) m = fmaxf(m, __shfl_xor(m, off, 64));
    float e0 = expf(s0 - m), e1 = expf(s1 - m);
    float sum = e0 + e1;
    #pragma unroll
    for (int off = 32; off >= 1; off >>= 1) sum += __shfl_xor(sum, off, 64);
    sc[b * 128 + lane] = e0 / sum;
    sc[b * 128 + 64 + lane] = e1 / sum;
}

__global__ __launch_bounds__(256) void mix_kernel(const float* __restrict__ mats,
                                                  const float* __restrict__ sc,
                                                  float* __restrict__ mixed)
{
    __shared__ float w[128];
    const int b = blockIdx.y, g = blockIdx.x, tid = threadIdx.x;
    if (tid < 128) w[tid] = sc[b * 128 + tid];
    __syncthreads();
    const int e = g * 256 + tid;
    float acc = 0.f;
    for (int i = 0; i < 128; ++i)
        acc += w[i] * mats[(size_t)(4096 + b * 128 + i) * 2304 + e];
    mixed[(size_t)b * 2304 + e] = acc;
}

// ---------------------------------------------------------------------------
// expm via scaling-squaring Taylor (s=2, degree 12). One block per b.
// ---------------------------------------------------------------------------
__global__ __launch_bounds__(256) void expm_kernel(const float* __restrict__ mixed,
                                                   float* __restrict__ out)
{
    __shared__ float Bs[48][49];
    __shared__ float Ra[48][49];
    __shared__ float Rb[48][49];
    const int b = blockIdx.x, tid = threadIdx.x;
    const float* M = mixed + (size_t)b * 2304;
    for (int e = tid; e < 2304; e += 256) {
        int r = e / 48, c = e % 48;
        float v = 0.25f * M[e];
        Bs[r][c] = v;
        Ra[r][c] = ((r == c) ? 1.f : 0.f) + v * (1.f / 12.f);
    }
    __syncthreads();
    const int tr = tid >> 4, tc = tid & 15;
    const int r0 = tr * 3, c0 = tc * 3;
    float* cur = &Ra[0][0];
    float* nxt = &Rb[0][0];
    for (int k = 11; k >= 1; --k) {
        const float invk = 1.f / (float)k;
        float acc[3][3];
        #pragma unroll
        for (int i = 0; i < 3; ++i)
            #pragma unroll
            for (int j = 0; j < 3; ++j) acc[i][j] = 0.f;
        #pragma unroll 4
        for (int kk = 0; kk < 48; ++kk) {
            float a0 = Bs[r0][kk], a1 = Bs[r0 + 1][kk], a2 = Bs[r0 + 2][kk];
            float b0 = cur[kk * 49 + c0], b1 = cur[kk * 49 + c0 + 1], b2 = cur[kk * 49 + c0 + 2];
            acc[0][0] += a0 * b0; acc[0][1] += a0 * b1; acc[0][2] += a0 * b2;
            acc[1][0] += a1 * b0; acc[1][1] += a1 * b1; acc[1][2] += a1 * b2;
            acc[2][0] += a2 * b0; acc[2][1] += a2 * b1; acc[2][2] += a2 * b2;
        }
        #pragma unroll
        for (int i = 0; i < 3; ++i)
            #pragma unroll
            for (int j = 0; j < 3; ++j)
                nxt[(r0 + i) * 49 + (c0 + j)] =
                    ((r0 + i) == (c0 + j) ? 1.f : 0.f) + acc[i][j] * invk;
        __syncthreads();
        float* t = cur; cur = nxt; nxt = t;
    }
    for (int sq = 0; sq < 2; ++sq) {
        float acc[3][3];
        #pragma unroll
        for (int i = 0; i < 3; ++i)
            #pragma unroll
            for (int j = 0; j < 3; ++j) acc[i][j] = 0.f;
        #pragma unroll 4
        for (int kk = 0; kk < 48; ++kk) {
            float a0 = cur[(r0) * 49 + kk], a1 = cur[(r0 + 1) * 49 + kk], a2 = cur[(r0 + 2) * 49 + kk];
            float b0 = cur[kk * 49 + c0], b1 = cur[kk * 49 + c0 + 1], b2 = cur[kk * 49 + c0 + 2];
            acc[0][0] += a0 * b0; acc[0][1] += a0 * b1; acc[0][2] += a0 * b2;
            acc[1][0] += a1 * b0; acc[1][1] += a1 * b1; acc[1][2] += a1 * b2;
            acc[2][0] += a2 * b0; acc[2][1] += a2 * b1; acc[2][2] += a2 * b2;
        }
        __syncthreads();
        #pragma unroll
        for (int i = 0; i < 3; ++i)
            #pragma unroll
            for (int j = 0; j < 3; ++j) nxt[(r0 + i) * 49 + (c0 + j)] = acc[i][j];
        __syncthreads();
        float* t = cur; cur = nxt; nxt = t;
    }
    #pragma unroll
    for (int i = 0; i < 3; ++i)
        #pragma unroll
        for (int j = 0; j < 3; ++j)
            out[(size_t)b * 2304 + (r0 + i) * 48 + (c0 + j)] = cur[(r0 + i) * 49 + (c0 + j)];
}

// ---------------------------------------------------------------------------
extern "C" void kernel_launch(void* const* d_in, const int* in_sizes, int n_in,
                              void* d_out, int out_size, void* d_ws, size_t ws_size,
                              hipStream_t stream)
{
    (void)in_sizes; (void)n_in; (void)out_size; (void)ws_size;
    const float* x1  = (const float*)d_in[0];
    const float* x2  = (const float*)d_in[1];
    const float* wk1 = (const float*)d_in[3];
    const float* wv1 = (const float*)d_in[4];
    const float* wq2 = (const float*)d_in[5];
    const float* wk2 = (const float*)d_in[6];
    const float* wv2 = (const float*)d_in[7];
    float* mats  = (float*)d_ws;                        // [8224][2304]
    float* mixed = mats + (size_t)8224 * 2304;          // [32][2304]
    float* scbuf = mixed + (size_t)32 * 2304;           // [32][128]
    unsigned short* whi = (unsigned short*)(scbuf + 4096);  // [5][4608]
    unsigned short* wlo = whi + 5 * 4608;
    float* out   = (float*)d_out;

    Cheb co;
    {
        const double a = 0.098, bb = 5.5;
        const int N = 256;
        for (int k = 0; k <= D_CHEB; ++k) {
            double sacc = 0.0;
            for (int j = 0; j < N; ++j) {
                double th = M_PI * (j + 0.5) / N;
                double xj = 0.5 * (a + bb) + 0.5 * (bb - a) * cos(th);
                sacc += log(xj) * cos(k * th);
            }
            double ck = 2.0 * sacc / N;
            if (k == 0) ck *= 0.5;
            if (k >= 1) ck *= 0.5;   // fold the final 0.5*S2 into all iterates
            co.c[k] = (float)ck;
        }
        co.sm  = (float)(4.0 / (bb - a));
        co.sbd = (float)((4.0 * 1e-6 - 2.0 * (a + bb)) / (bb - a));
    }

    split_w<<<5, 256, 0, stream>>>(wk1, wv1, wk2, wv2, wq2, whi, wlo);
    bimap_kernel<<<4128, 64, 0, stream>>>(x1, x2, whi, wlo, mats);
    logm_kernel<<<8224, 64, 0, stream>>>(mats, co);
    energy_kernel<<<dim3(128, 32), 64, 0, stream>>>(mats, scbuf);
    softmax_kernel<<<32, 64, 0, stream>>>(scbuf);
    mix_kernel<<<dim3(9, 32), 256, 0, stream>>>(mats, scbuf, mixed);
    expm_kernel<<<32, 256, 0, stream>>>(mixed, out);
}

// Round 5
// 415.220 us; speedup vs baseline: 4.6412x; 1.0514x over previous
//
#include <hip/hip_runtime.h>
#include <math.h>

#define D_CHEB 24

typedef __attribute__((ext_vector_type(8))) short bf16x8;
typedef __attribute__((ext_vector_type(4))) short bf16x4;
typedef __attribute__((ext_vector_type(4))) float f32x4;
typedef __attribute__((ext_vector_type(4))) unsigned int u32x4;
typedef __attribute__((ext_vector_type(2))) unsigned int u32x2;

#if __has_builtin(__builtin_amdgcn_mfma_f32_16x16x16bf16_1k)
#define HAVE_MFMA16 1
#else
#define HAVE_MFMA16 0
#endif

struct Cheb {
    float c[D_CHEB + 1];  // c[1..D] pre-halved on host (b' = 0.5 b trick)
    float sm;   // S2 = sm*A + sbd*I
    float sbd;
};

// split 8 f32 (two f32x4) into bf16 hi (RNE) + lo (trunc of residual)
__device__ __forceinline__ void split8(const f32x4 a, const f32x4 b,
                                       bf16x8& hi, bf16x8& lo)
{
    float v[8] = {a[0], a[1], a[2], a[3], b[0], b[1], b[2], b[3]};
    unsigned h16[8], l16[8];
    #pragma unroll
    for (int j = 0; j < 8; ++j) {
        unsigned u = __float_as_uint(v[j]);
        unsigned r = (u + 0x7FFFu + ((u >> 16) & 1u)) >> 16;   // RNE to bf16
        h16[j] = r;
        float res = v[j] - __uint_as_float(r << 16);
        l16[j] = __float_as_uint(res) >> 16;                    // trunc residual
    }
    unsigned hw[4], lw[4];
    #pragma unroll
    for (int q = 0; q < 4; ++q) {
        hw[q] = h16[2 * q] | (h16[2 * q + 1] << 16);
        lw[q] = l16[2 * q] | (l16[2 * q + 1] << 16);
    }
    hi = __builtin_bit_cast(bf16x8, (u32x4){hw[0], hw[1], hw[2], hw[3]});
    lo = __builtin_bit_cast(bf16x8, (u32x4){lw[0], lw[1], lw[2], lw[3]});
}

// ---------------------------------------------------------------------------
// split W (48x96 row-major f32) -> bf16 hi/lo, 5 matrices
// ---------------------------------------------------------------------------
__global__ __launch_bounds__(256) void split_w(
    const float* __restrict__ w0, const float* __restrict__ w1,
    const float* __restrict__ w2, const float* __restrict__ w3,
    const float* __restrict__ w4,
    unsigned short* __restrict__ whi, unsigned short* __restrict__ wlo)
{
    const float* W = (blockIdx.x == 0) ? w0 : (blockIdx.x == 1) ? w1
                   : (blockIdx.x == 2) ? w2 : (blockIdx.x == 3) ? w3 : w4;
    const int base = blockIdx.x * 4608;
    for (int e = threadIdx.x; e < 4608; e += 256) {
        float f = W[e];
        unsigned u = __float_as_uint(f);
        unsigned r = (u + 0x7FFFu + ((u >> 16) & 1u)) >> 16;
        whi[base + e] = (unsigned short)r;
        float res = f - __uint_as_float(r << 16);
        wlo[base + e] = (unsigned short)(__float_as_uint(res) >> 16);
    }
}

// ---------------------------------------------------------------------------
// bimap via split-bf16 MFMA: out = W x W^T. One wave per matrix(-pair).
// ---------------------------------------------------------------------------
#define TLP 104   // T row pitch (f32)
__global__ __launch_bounds__(64, 3) void bimap_kernel(
    const float* __restrict__ x1, const float* __restrict__ x2,
    const unsigned short* __restrict__ whi,
    const unsigned short* __restrict__ wlo,
    float* __restrict__ mats)
{
    __shared__ float Tlds[48 * TLP];
    const int bid = blockIdx.x, l = threadIdx.x;
    const int lc = l & 15, lg = l >> 4;

    const float* x; int wi[2]; size_t oo[2]; int npass;
    if (bid < 4096) {
        int b = bid >> 7, s = (bid >> 6) & 1, m = bid & 63;
        x = (s ? x2 : x1) + (size_t)(b * 64 + m) * 9216;
        wi[0] = s ? 2 : 0;  // wk
        wi[1] = s ? 3 : 1;  // wv
        oo[0] = (size_t)bid; oo[1] = (size_t)(4096 + bid); npass = 2;
    } else {
        int b = bid - 4096;
        x = x2 + (size_t)(b * 64 + 63) * 9216;
        wi[0] = 4; wi[1] = 4;
        oo[0] = (size_t)(8192 + b); oo[1] = oo[0]; npass = 1;
    }

    for (int pass = 0; pass < npass; ++pass) {
        const unsigned short* Wh = whi + wi[pass] * 4608;
        const unsigned short* Wl = wlo + wi[pass] * 4608;

        // ---- phase 1: T(48x96) = W @ x, K=96 ----
        f32x4 C[3][6];
        #pragma unroll
        for (int tr = 0; tr < 3; ++tr)
            #pragma unroll
            for (int tc = 0; tc < 6; ++tc)
                C[tr][tc] = (f32x4){0.f, 0.f, 0.f, 0.f};
        #pragma unroll
        for (int kb = 0; kb < 3; ++kb) {
            bf16x8 ah[3], al[3];
            #pragma unroll
            for (int tr = 0; tr < 3; ++tr) {
                const int off = (16 * tr + lc) * 96 + kb * 32 + lg * 8;
                ah[tr] = *(const bf16x8*)(Wh + off);
                al[tr] = *(const bf16x8*)(Wl + off);
            }
            #pragma unroll
            for (int tc = 0; tc < 6; ++tc) {
                const float* xp = x + (16 * tc + lc) * 96 + kb * 32 + lg * 8;
                bf16x8 bh, bl;
                split8(*(const f32x4*)xp, *(const f32x4*)(xp + 4), bh, bl);
                #pragma unroll
                for (int tr = 0; tr < 3; ++tr) {
                    C[tr][tc] = __builtin_amdgcn_mfma_f32_16x16x32_bf16(ah[tr], bh, C[tr][tc], 0, 0, 0);
                    C[tr][tc] = __builtin_amdgcn_mfma_f32_16x16x32_bf16(ah[tr], bl, C[tr][tc], 0, 0, 0);
                    C[tr][tc] = __builtin_amdgcn_mfma_f32_16x16x32_bf16(al[tr], bh, C[tr][tc], 0, 0, 0);
                }
            }
        }
        #pragma unroll
        for (int tr = 0; tr < 3; ++tr)
            #pragma unroll
            for (int tc = 0; tc < 6; ++tc)
                #pragma unroll
                for (int q = 0; q < 4; ++q)
                    Tlds[(16 * tr + 4 * lg + q) * TLP + 16 * tc + lc] = C[tr][tc][q];

        // ---- phase 2: out(48x48) = T @ W^T, K=96 ----
        f32x4 D[3][3];
        #pragma unroll
        for (int tr = 0; tr < 3; ++tr)
            #pragma unroll
            for (int tc = 0; tc < 3; ++tc)
                D[tr][tc] = (f32x4){0.f, 0.f, 0.f, 0.f};
        #pragma unroll
        for (int kb = 0; kb < 3; ++kb) {
            bf16x8 ah[3], al[3];
            #pragma unroll
            for (int tr = 0; tr < 3; ++tr) {
                const float* tp = &Tlds[(16 * tr + lc) * TLP + kb * 32 + lg * 8];
                split8(*(const f32x4*)tp, *(const f32x4*)(tp + 4), ah[tr], al[tr]);
            }
            #pragma unroll
            for (int tc = 0; tc < 3; ++tc) {
                const int off = (16 * tc + lc) * 96 + kb * 32 + lg * 8;
                bf16x8 bh = *(const bf16x8*)(Wh + off);
                bf16x8 bl = *(const bf16x8*)(Wl + off);
                #pragma unroll
                for (int tr = 0; tr < 3; ++tr) {
                    D[tr][tc] = __builtin_amdgcn_mfma_f32_16x16x32_bf16(ah[tr], bh, D[tr][tc], 0, 0, 0);
                    D[tr][tc] = __builtin_amdgcn_mfma_f32_16x16x32_bf16(ah[tr], bl, D[tr][tc], 0, 0, 0);
                    D[tr][tc] = __builtin_amdgcn_mfma_f32_16x16x32_bf16(al[tr], bh, D[tr][tc], 0, 0, 0);
                }
            }
        }
        float* out = mats + oo[pass] * 2304;
        #pragma unroll
        for (int tr = 0; tr < 3; ++tr)
            #pragma unroll
            for (int tc = 0; tc < 3; ++tc)
                #pragma unroll
                for (int q = 0; q < 4; ++q)
                    out[(16 * tr + 4 * lg + q) * 48 + 16 * tc + lc] = D[tr][tc][q];
    }
}

// ---------------------------------------------------------------------------
// logm: Chebyshev-Clenshaw via split-bf16 MFMA. One wave per matrix, in-place.
// Symmetry twice: (1) both MFMA operands read rows; (2) C-tiles are written
// TRANSPOSED so each lane's 4 values are one contiguous ds_write_b64.
// K=48 handled as K=32 MFMA + K=16 MFMA tail (if builtin available).
// ---------------------------------------------------------------------------
__global__ __launch_bounds__(64, 3) void logm_kernel(float* __restrict__ mats, Cheb co)
{
    __shared__ __align__(16) unsigned short Ybuf[2 * 48 * 64];  // hi @0, lo @+6144B
    char* ldsb = (char*)Ybuf;
    const int l = threadIdx.x;
    const int lc = l & 15, lg = l >> 4;
    const int rloc = lg * 4;
    float* A = mats + (size_t)blockIdx.x * 2304;

    // ---- A-frags (S2 split) in registers + seed LDS with split(b'_{D-1}) ----
    bf16x8 Ah[3][2], Al[3][2];
    const float cD = co.c[D_CHEB], cD1 = co.c[D_CHEB - 1];
    #pragma unroll
    for (int tr = 0; tr < 3; ++tr) {
        #pragma unroll
        for (int kb = 0; kb < 2; ++kb) {
            const int row = 16 * tr + lc;
            const int k0 = kb * 32 + lg * 8;
            unsigned shw[4] = {0,0,0,0}, slw[4] = {0,0,0,0};
            unsigned yhw[4] = {0,0,0,0}, ylw[4] = {0,0,0,0};
            if (k0 < 48) {
                const float* ap = A + row * 48 + k0;
                f32x4 a0 = *(const f32x4*)ap;
                f32x4 a1 = *(const f32x4*)(ap + 4);
                float av[8] = {a0[0],a0[1],a0[2],a0[3],a1[0],a1[1],a1[2],a1[3]};
                unsigned sh[8], sl[8], yh[8], yl[8];
                #pragma unroll
                for (int j = 0; j < 8; ++j) {
                    const bool diag = (row == k0 + j);
                    float s = co.sm * av[j] + (diag ? co.sbd : 0.f);
                    float y = cD * s + (diag ? cD1 : 0.f);
                    unsigned us = __float_as_uint(s);
                    sh[j] = us >> 16;
                    sl[j] = __float_as_uint(s - __uint_as_float(us & 0xFFFF0000u)) >> 16;
                    unsigned uy = __float_as_uint(y);
                    yh[j] = uy >> 16;
                    yl[j] = __float_as_uint(y - __uint_as_float(uy & 0xFFFF0000u)) >> 16;
                }
                #pragma unroll
                for (int q = 0; q < 4; ++q) {
                    shw[q] = sh[2*q] | (sh[2*q+1] << 16);
                    slw[q] = sl[2*q] | (sl[2*q+1] << 16);
                    yhw[q] = yh[2*q] | (yh[2*q+1] << 16);
                    ylw[q] = yl[2*q] | (yl[2*q+1] << 16);
                }
            }
            Ah[tr][kb] = __builtin_bit_cast(bf16x8, (u32x4){shw[0],shw[1],shw[2],shw[3]});
            Al[tr][kb] = __builtin_bit_cast(bf16x8, (u32x4){slw[0],slw[1],slw[2],slw[3]});
            const int soff = row * 128 + ((2 * k0) ^ ((row & 7) << 4));
            *(u32x4*)(ldsb + soff)        = (u32x4){yhw[0],yhw[1],yhw[2],yhw[3]};
            *(u32x4*)(ldsb + 6144 + soff) = (u32x4){ylw[0],ylw[1],ylw[2],ylw[3]};
        }
    }

#if HAVE_MFMA16
    // ---- K=16 tail A-frags: S2[row][32 + 4*lg + j], j=0..3 ----
    bf16x4 Ath[3], Atl[3];
    #pragma unroll
    for (int tr = 0; tr < 3; ++tr) {
        const int row = 16 * tr + lc;
        const int k0 = 32 + 4 * lg;
        f32x4 a = *(const f32x4*)(A + row * 48 + k0);
        unsigned sh[4], sl[4];
        #pragma unroll
        for (int j = 0; j < 4; ++j) {
            const bool diag = (row == k0 + j);
            float s = co.sm * a[j] + (diag ? co.sbd : 0.f);
            unsigned us = __float_as_uint(s);
            sh[j] = us >> 16;
            sl[j] = __float_as_uint(s - __uint_as_float(us & 0xFFFF0000u)) >> 16;
        }
        Ath[tr] = __builtin_bit_cast(bf16x4, (u32x2){sh[0] | (sh[1] << 16), sh[2] | (sh[3] << 16)});
        Atl[tr] = __builtin_bit_cast(bf16x4, (u32x2){sl[0] | (sl[1] << 16), sl[2] | (sl[3] << 16)});
    }
#endif

    // ---- seed C-layout registers: Ya = b'_{D-1} = cD1*I + cD*S2 ; Yb = cD*I
    f32x4 Ya[9], Yb[9];
    #pragma unroll
    for (int t = 0; t < 9; ++t) {
        const int tr = t / 3, tc = t % 3;
        #pragma unroll
        for (int q = 0; q < 4; ++q) {
            const int row = 16 * tr + rloc + q, col = 16 * tc + lc;
            const bool diag = (row == col);
            float a = A[row * 48 + col];
            float s = co.sm * a + (diag ? co.sbd : 0.f);
            Ya[t][q] = cD * s + (diag ? cD1 : 0.f);
            Yb[t][q] = diag ? cD : 0.f;
        }
    }

    // ---- precomputed per-lane LDS byte offsets ----
    int boff0[3];     // K=32 chunk reads: row = 16tc+lc, bytes lg*16
    int bofft[3];     // K=16 tail reads:  row = 16tc+lc, bytes 64 + lg*8
    int boff1[3];     // fallback K=32 pad chunk: bytes 64 + lg*16
    #pragma unroll
    for (int tc = 0; tc < 3; ++tc) {
        const int row = 16 * tc + lc;
        const int sw = (row & 7) << 4;
        boff0[tc] = row * 128 + ((lg * 16) ^ sw);
        bofft[tc] = row * 128 + ((64 + lg * 8) ^ sw);
        boff1[tc] = row * 128 + ((64 + lg * 16) ^ sw);
    }
    int woffT[9];     // transposed writes: tile (tr,tc) -> row'=16tc+lc, bytes 32tr+8lg
    #pragma unroll
    for (int t = 0; t < 9; ++t) {
        const int tr = t / 3, tc = t % 3;
        const int row = 16 * tc + lc;
        woffT[t] = row * 128 + (((32 * tr + 8 * lg)) ^ ((row & 7) << 4));
    }

    auto MM = [&](f32x4 (&T)[9]) {
        #pragma unroll
        for (int tc = 0; tc < 3; ++tc) {
            {   // K chunk 0..31 (16x16x32)
                bf16x8 bh = *(const bf16x8*)(ldsb + boff0[tc]);
                bf16x8 bl = *(const bf16x8*)(ldsb + 6144 + boff0[tc]);
                #pragma unroll
                for (int tr = 0; tr < 3; ++tr)
                    T[tr*3+tc] = __builtin_amdgcn_mfma_f32_16x16x32_bf16(Ah[tr][0], bh, T[tr*3+tc], 0, 0, 0);
                #pragma unroll
                for (int tr = 0; tr < 3; ++tr)
                    T[tr*3+tc] = __builtin_amdgcn_mfma_f32_16x16x32_bf16(Ah[tr][0], bl, T[tr*3+tc], 0, 0, 0);
                #pragma unroll
                for (int tr = 0; tr < 3; ++tr)
                    T[tr*3+tc] = __builtin_amdgcn_mfma_f32_16x16x32_bf16(Al[tr][0], bh, T[tr*3+tc], 0, 0, 0);
            }
#if HAVE_MFMA16
            {   // K chunk 32..47 (16x16x16 tail)
                bf16x4 bh = *(const bf16x4*)(ldsb + bofft[tc]);
                bf16x4 bl = *(const bf16x4*)(ldsb + 6144 + bofft[tc]);
                #pragma unroll
                for (int tr = 0; tr < 3; ++tr)
                    T[tr*3+tc] = __builtin_amdgcn_mfma_f32_16x16x16bf16_1k(Ath[tr], bh, T[tr*3+tc], 0, 0, 0);
                #pragma unroll
                for (int tr = 0; tr < 3; ++tr)
                    T[tr*3+tc] = __builtin_amdgcn_mfma_f32_16x16x16bf16_1k(Ath[tr], bl, T[tr*3+tc], 0, 0, 0);
                #pragma unroll
                for (int tr = 0; tr < 3; ++tr)
                    T[tr*3+tc] = __builtin_amdgcn_mfma_f32_16x16x16bf16_1k(Atl[tr], bh, T[tr*3+tc], 0, 0, 0);
            }
#else
            {   // K chunk 32..63 (padded, pad region zero-seeded)
                bf16x8 bh = *(const bf16x8*)(ldsb + boff1[tc]);
                bf16x8 bl = *(const bf16x8*)(ldsb + 6144 + boff1[tc]);
                #pragma unroll
                for (int tr = 0; tr < 3; ++tr)
                    T[tr*3+tc] = __builtin_amdgcn_mfma_f32_16x16x32_bf16(Ah[tr][1], bh, T[tr*3+tc], 0, 0, 0);
                #pragma unroll
                for (int tr = 0; tr < 3; ++tr)
                    T[tr*3+tc] = __builtin_amdgcn_mfma_f32_16x16x32_bf16(Ah[tr][1], bl, T[tr*3+tc], 0, 0, 0);
                #pragma unroll
                for (int tr = 0; tr < 3; ++tr)
                    T[tr*3+tc] = __builtin_amdgcn_mfma_f32_16x16x32_bf16(Al[tr][1], bh, T[tr*3+tc], 0, 0, 0);
            }
#endif
        }
    };
    // transposed packed write: stored = C^T (valid: all iterates symmetric)
    auto SPLITWT = [&](f32x4 (&T)[9]) {
        #pragma unroll
        for (int t = 0; t < 9; ++t) {
            unsigned u0 = __float_as_uint(T[t][0]);
            unsigned u1 = __float_as_uint(T[t][1]);
            unsigned u2 = __float_as_uint(T[t][2]);
            unsigned u3 = __float_as_uint(T[t][3]);
            unsigned h01 = (u1 & 0xFFFF0000u) | (u0 >> 16);
            unsigned h23 = (u3 & 0xFFFF0000u) | (u2 >> 16);
            float r0 = T[t][0] - __uint_as_float(u0 & 0xFFFF0000u);
            float r1 = T[t][1] - __uint_as_float(u1 & 0xFFFF0000u);
            float r2 = T[t][2] - __uint_as_float(u2 & 0xFFFF0000u);
            float r3 = T[t][3] - __uint_as_float(u3 & 0xFFFF0000u);
            unsigned l01 = (__float_as_uint(r1) & 0xFFFF0000u) | (__float_as_uint(r0) >> 16);
            unsigned l23 = (__float_as_uint(r3) & 0xFFFF0000u) | (__float_as_uint(r2) >> 16);
            const int off = woffT[t];
            *(u32x2*)(ldsb + off)        = (u32x2){h01, h23};
            *(u32x2*)(ldsb + 6144 + off) = (u32x2){l01, l23};
        }
    };
    auto INITK = [&](f32x4 (&T)[9], float ck) {
        #pragma unroll
        for (int t = 0; t < 9; ++t) {
            const int tr = t / 3, tc = t % 3;
            #pragma unroll
            for (int q = 0; q < 4; ++q) {
                const float d = (tr == tc && rloc + q == lc) ? ck : 0.f;
                T[t][q] = d - T[t][q];
            }
        }
    };

    // ---- Clenshaw: b'_k = c'_k I − b'_{k+2} + S2 @ b'_{k+1} ----
    for (int k = D_CHEB - 2; k >= 2; k -= 2) {
        INITK(Yb, co.c[k]);     MM(Yb);  SPLITWT(Yb);
        INITK(Ya, co.c[k - 1]); MM(Ya);  SPLITWT(Ya);
    }
    // ---- final: log = c0 I − 2 b'_2 + S2 @ b'_1  (b'_1 split is in LDS) ----
    #pragma unroll
    for (int t = 0; t < 9; ++t) {
        const int tr = t / 3, tc = t % 3;
        #pragma unroll
        for (int q = 0; q < 4; ++q) {
            const float d = (tr == tc && rloc + q == lc) ? co.c[0] : 0.f;
            Yb[t][q] = d - 2.f * Yb[t][q];
        }
    }
    MM(Yb);
    #pragma unroll
    for (int t = 0; t < 9; ++t) {
        const int tr = t / 3, tc = t % 3;
        #pragma unroll
        for (int q = 0; q < 4; ++q)
            A[(16 * tr + rloc + q) * 48 + 16 * tc + lc] = Yb[t][q];
    }
}

// ---------------------------------------------------------------------------
// attention, split: energy (4096 waves) -> softmax (32 waves) -> mix (288 blk)
// ---------------------------------------------------------------------------
__global__ __launch_bounds__(64) void energy_kernel(const float* __restrict__ mats,
                                                    float* __restrict__ sc)
{
    const int i = blockIdx.x, b = blockIdx.y, lane = threadIdx.x;
    const float* K = mats + (size_t)(b * 128 + i) * 2304;
    const float* Q = mats + (size_t)(8192 + b) * 2304;
    float p = 0.f;
    #pragma unroll
    for (int j = 0; j < 9; ++j) {
        int f = (lane + 64 * j) * 4;
        float4 kv = *(const float4*)(K + f);
        float4 qv = *(const float4*)(Q + f);
        float dx = kv.x - qv.x, dy = kv.y - qv.y, dz = kv.z - qv.z, dw = kv.w - qv.w;
        p += dx * dx + dy * dy + dz * dz + dw * dw;
    }
    #pragma unroll
    for (int off = 32; off >= 1; off >>= 1) p += __shfl_xor(p, off, 64);
    if (lane == 0)
        sc[b * 128 + i] = 1.f / (1.f + log1pf(fmaxf(p, 0.f)));
}

__global__ __launch_bounds__(64) void softmax_kernel(float* __restrict__ sc)
{
    const int b = blockIdx.x, lane = threadIdx.x;
    float s0 = sc[b * 128 + lane], s1 = sc[b * 128 + 64 + lane];
    float m = fmaxf(s0, s1);
    #pragma unroll
    for (int off = 32; off >= 1; off >>= 1) m = fmaxf(m, __shfl_xor(m, off, 64));
    float e0 = expf(s0 - m), e1 = expf(s1 - m);
    float sum = e0 + e1;
    #pragma unroll
    for (int off = 32; off >= 1; off >>= 1) sum += __shfl_xor(sum, off, 64);
    sc[b * 128 + lane] = e0 / sum;
    sc[b * 128 + 64 + lane] = e1 / sum;
}

__global__ __launch_bounds__(256) void mix_kernel(const float* __restrict__ mats,
                                                  const float* __restrict__ sc,
                                                  float* __restrict__ mixed)
{
    __shared__ float w[128];
    const int b = blockIdx.y, g = blockIdx.x, tid = threadIdx.x;
    if (tid < 128) w[tid] = sc[b * 128 + tid];
    __syncthreads();
    const int e = g * 256 + tid;
    float acc = 0.f;
    for (int i = 0; i < 128; ++i)
        acc += w[i] * mats[(size_t)(4096 + b * 128 + i) * 2304 + e];
    mixed[(size_t)b * 2304 + e] = acc;
}

// ---------------------------------------------------------------------------
// expm via scaling-squaring Taylor (s=2, degree 12). One block per b.
// ---------------------------------------------------------------------------
__global__ __launch_bounds__(256) void expm_kernel(const float* __restrict__ mixed,
                                                   float* __restrict__ out)
{
    __shared__ float Bs[48][49];
    __shared__ float Ra[48][49];
    __shared__ float Rb[48][49];
    const int b = blockIdx.x, tid = threadIdx.x;
    const float* M = mixed + (size_t)b * 2304;
    for (int e = tid; e < 2304; e += 256) {
        int r = e / 48, c = e % 48;
        float v = 0.25f * M[e];
        Bs[r][c] = v;
        Ra[r][c] = ((r == c) ? 1.f : 0.f) + v * (1.f / 12.f);
    }
    __syncthreads();
    const int tr = tid >> 4, tc = tid & 15;
    const int r0 = tr * 3, c0 = tc * 3;
    float* cur = &Ra[0][0];
    float* nxt = &Rb[0][0];
    for (int k = 11; k >= 1; --k) {
        const float invk = 1.f / (float)k;
        float acc[3][3];
        #pragma unroll
        for (int i = 0; i < 3; ++i)
            #pragma unroll
            for (int j = 0; j < 3; ++j) acc[i][j] = 0.f;
        #pragma unroll 4
        for (int kk = 0; kk < 48; ++kk) {
            float a0 = Bs[r0][kk], a1 = Bs[r0 + 1][kk], a2 = Bs[r0 + 2][kk];
            float b0 = cur[kk * 49 + c0], b1 = cur[kk * 49 + c0 + 1], b2 = cur[kk * 49 + c0 + 2];
            acc[0][0] += a0 * b0; acc[0][1] += a0 * b1; acc[0][2] += a0 * b2;
            acc[1][0] += a1 * b0; acc[1][1] += a1 * b1; acc[1][2] += a1 * b2;
            acc[2][0] += a2 * b0; acc[2][1] += a2 * b1; acc[2][2] += a2 * b2;
        }
        #pragma unroll
        for (int i = 0; i < 3; ++i)
            #pragma unroll
            for (int j = 0; j < 3; ++j)
                nxt[(r0 + i) * 49 + (c0 + j)] =
                    ((r0 + i) == (c0 + j) ? 1.f : 0.f) + acc[i][j] * invk;
        __syncthreads();
        float* t = cur; cur = nxt; nxt = t;
    }
    for (int sq = 0; sq < 2; ++sq) {
        float acc[3][3];
        #pragma unroll
        for (int i = 0; i < 3; ++i)
            #pragma unroll
            for (int j = 0; j < 3; ++j) acc[i][j] = 0.f;
        #pragma unroll 4
        for (int kk = 0; kk < 48; ++kk) {
            float a0 = cur[(r0) * 49 + kk], a1 = cur[(r0 + 1) * 49 + kk], a2 = cur[(r0 + 2) * 49 + kk];
            float b0 = cur[kk * 49 + c0], b1 = cur[kk * 49 + c0 + 1], b2 = cur[kk * 49 + c0 + 2];
            acc[0][0] += a0 * b0; acc[0][1] += a0 * b1; acc[0][2] += a0 * b2;
            acc[1][0] += a1 * b0; acc[1][1] += a1 * b1; acc[1][2] += a1 * b2;
            acc[2][0] += a2 * b0; acc[2][1] += a2 * b1; acc[2][2] += a2 * b2;
        }
        __syncthreads();
        #pragma unroll
        for (int i = 0; i < 3; ++i)
            #pragma unroll
            for (int j = 0; j < 3; ++j) nxt[(r0 + i) * 49 + (c0 + j)] = acc[i][j];
        __syncthreads();
        float* t = cur; cur = nxt; nxt = t;
    }
    #pragma unroll
    for (int i = 0; i < 3; ++i)
        #pragma unroll
        for (int j = 0; j < 3; ++j)
            out[(size_t)b * 2304 + (r0 + i) * 48 + (c0 + j)] = cur[(r0 + i) * 49 + (c0 + j)];
}

// ---------------------------------------------------------------------------
extern "C" void kernel_launch(void* const* d_in, const int* in_sizes, int n_in,
                              void* d_out, int out_size, void* d_ws, size_t ws_size,
                              hipStream_t stream)
{
    (void)in_sizes; (void)n_in; (void)out_size; (void)ws_size;
    const float* x1  = (const float*)d_in[0];
    const float* x2  = (const float*)d_in[1];
    const float* wk1 = (const float*)d_in[3];
    const float* wv1 = (const float*)d_in[4];
    const float* wq2 = (const float*)d_in[5];
    const float* wk2 = (const float*)d_in[6];
    const float* wv2 = (const float*)d_in[7];
    float* mats  = (float*)d_ws;                        // [8224][2304]
    float* mixed = mats + (size_t)8224 * 2304;          // [32][2304]
    float* scbuf = mixed + (size_t)32 * 2304;           // [32][128]
    unsigned short* whi = (unsigned short*)(scbuf + 4096);  // [5][4608]
    unsigned short* wlo = whi + 5 * 4608;
    float* out   = (float*)d_out;

    Cheb co;
    {
        const double a = 0.098, bb = 5.5;
        const int N = 256;
        for (int k = 0; k <= D_CHEB; ++k) {
            double sacc = 0.0;
            for (int j = 0; j < N; ++j) {
                double th = M_PI * (j + 0.5) / N;
                double xj = 0.5 * (a + bb) + 0.5 * (bb - a) * cos(th);
                sacc += log(xj) * cos(k * th);
            }
            double ck = 2.0 * sacc / N;
            if (k == 0) ck *= 0.5;
            if (k >= 1) ck *= 0.5;   // fold the final 0.5*S2 into all iterates
            co.c[k] = (float)ck;
        }
        co.sm  = (float)(4.0 / (bb - a));
        co.sbd = (float)((4.0 * 1e-6 - 2.0 * (a + bb)) / (bb - a));
    }

    split_w<<<5, 256, 0, stream>>>(wk1, wv1, wk2, wv2, wq2, whi, wlo);
    bimap_kernel<<<4128, 64, 0, stream>>>(x1, x2, whi, wlo, mats);
    logm_kernel<<<8224, 64, 0, stream>>>(mats, co);
    energy_kernel<<<dim3(128, 32), 64, 0, stream>>>(mats, scbuf);
    softmax_kernel<<<32, 64, 0, stream>>>(scbuf);
    mix_kernel<<<dim3(9, 32), 256, 0, stream>>>(mats, scbuf, mixed);
    expm_kernel<<<32, 256, 0, stream>>>(mixed, out);
}